// Round 1
// baseline (1470.400 us; speedup 1.0000x reference)
//
#include <hip/hip_runtime.h>
#include <stdint.h>

typedef __bf16 bf16x8 __attribute__((ext_vector_type(8)));
typedef float f32x4 __attribute__((ext_vector_type(4)));

__device__ __forceinline__ float b2f(uint32_t u) {
  union { uint32_t i; float f; } v; v.i = u << 16; return v.f;
}
__device__ __forceinline__ uint16_t f2b(float f) {
  union { float f; uint32_t i; } v; v.f = f;
  uint32_t r = (v.i + 0x7fffu + ((v.i >> 16) & 1u)) >> 16;
  return (uint16_t)r;
}
__device__ __forceinline__ void unpack8(uint4 u, float* f) {
  f[0] = b2f(u.x & 0xffffu); f[1] = b2f(u.x >> 16);
  f[2] = b2f(u.y & 0xffffu); f[3] = b2f(u.y >> 16);
  f[4] = b2f(u.z & 0xffffu); f[5] = b2f(u.z >> 16);
  f[6] = b2f(u.w & 0xffffu); f[7] = b2f(u.w >> 16);
}

// ---------------- Generic bf16 GEMM: C(MxN) = A(MxK) * Bt(NxK)^T ----------------
// mode 0: outb[r*N+c] = bf16(acc + bias[c])
// mode 1: outf[r*N+c] = resid[r*N+c] + gate[(r>>12)*10368 + c] * (acc + bias[c])
__global__ __launch_bounds__(256) void gemm_k(
    const uint16_t* __restrict__ A, const uint16_t* __restrict__ Bt,
    const float* __restrict__ bias,
    uint16_t* __restrict__ outb,
    float* __restrict__ outf, const float* __restrict__ resid,
    const float* __restrict__ gate,
    int M, int N, int K, int mode)
{
  __shared__ __align__(16) uint16_t As[128 * 40];
  __shared__ __align__(16) uint16_t Bs[128 * 40];
  const int tid = threadIdx.x;
  const int row0 = blockIdx.y * 128, col0 = blockIdx.x * 128;
  const int lane = tid & 63, wave = tid >> 6;
  const int l15 = lane & 15, quad = lane >> 4;
  const int wm = (wave & 1) * 64, wn = (wave >> 1) * 64;
  const int r = tid >> 1, kh = (tid & 1) * 16;

  f32x4 acc[4][4];
  const f32x4 zero = {0.f, 0.f, 0.f, 0.f};
  for (int i = 0; i < 4; i++)
    for (int j = 0; j < 4; j++)
      acc[i][j] = zero;

  const uint16_t* ga = A + (size_t)(row0 + r) * K + kh;
  const uint16_t* gb = Bt + (size_t)(col0 + r) * K + kh;

  for (int k0 = 0; k0 < K; k0 += 32) {
    const uint4 av0 = *(const uint4*)(ga + k0);
    const uint4 av1 = *(const uint4*)(ga + k0 + 8);
    const uint4 bv0 = *(const uint4*)(gb + k0);
    const uint4 bv1 = *(const uint4*)(gb + k0 + 8);
    __syncthreads();
    *(uint4*)&As[r * 40 + kh]     = av0;
    *(uint4*)&As[r * 40 + kh + 8] = av1;
    *(uint4*)&Bs[r * 40 + kh]     = bv0;
    *(uint4*)&Bs[r * 40 + kh + 8] = bv1;
    __syncthreads();

    bf16x8 af[4], bfr[4];
#pragma unroll
    for (int i = 0; i < 4; i++) {
      af[i]  = *(const bf16x8*)&As[(wm + i * 16 + l15) * 40 + quad * 8];
      bfr[i] = *(const bf16x8*)&Bs[(wn + i * 16 + l15) * 40 + quad * 8];
    }
#pragma unroll
    for (int mi = 0; mi < 4; mi++)
#pragma unroll
      for (int ni = 0; ni < 4; ni++)
        acc[mi][ni] = __builtin_amdgcn_mfma_f32_16x16x32_bf16(af[mi], bfr[ni], acc[mi][ni], 0, 0, 0);
  }

#pragma unroll
  for (int mi = 0; mi < 4; mi++) {
#pragma unroll
    for (int ni = 0; ni < 4; ni++) {
      const int colg = col0 + wn + ni * 16 + l15;
      const float bv = bias ? bias[colg] : 0.f;
#pragma unroll
      for (int i = 0; i < 4; i++) {
        const int rowg = row0 + wm + mi * 16 + quad * 4 + i;
        const float v = acc[mi][ni][i] + bv;
        const size_t idx = (size_t)rowg * N + colg;
        if (mode == 0) {
          outb[idx] = f2b(v);
        } else {
          const int b = rowg >> 12;  // T*L = 4096 rows per batch
          outf[idx] = resid[idx] + gate[b * 10368 + colg] * v;
        }
      }
    }
  }
}

// ---------------- RMS + adaLN modulate: xn = rms(x)*w*(1+sc) + sh -> bf16 ----------------
__global__ __launch_bounds__(256) void rmsnorm_k(
    const float* __restrict__ x, const float* __restrict__ w,
    const float* __restrict__ chv, int shsel, int scsel,
    uint16_t* __restrict__ xn)
{
  const int row = blockIdx.x;
  const int b = row >> 12;
  const float* xr = x + (size_t)row * 1152;
  float ss = 0.f;
  for (int d = threadIdx.x; d < 1152; d += 256) { const float v = xr[d]; ss += v * v; }
  for (int off = 32; off > 0; off >>= 1) ss += __shfl_down(ss, off);
  __shared__ float red[4];
  if ((threadIdx.x & 63) == 0) red[threadIdx.x >> 6] = ss;
  __syncthreads();
  const float tot = red[0] + red[1] + red[2] + red[3];
  const float rs = rsqrtf(tot * (1.f / 1152.f) + 1e-6f);
  const float* sh = chv + b * 10368 + shsel * 1152;
  const float* sc = chv + b * 10368 + scsel * 1152;
  uint16_t* xo = xn + (size_t)row * 1152;
  for (int d = threadIdx.x; d < 1152; d += 256)
    xo[d] = f2b(xr[d] * rs * w[d] * (1.f + sc[d]) + sh[d]);
}

// ---------------- per-head RMS norm of q,k inside qkv buffer (in place) ----------------
__global__ __launch_bounds__(256) void qknorm_k(
    uint16_t* __restrict__ qkv, const float* __restrict__ qn, const float* __restrict__ kn)
{
  const int tid = threadIdx.x;
  const int rl = tid >> 5, unit = tid & 31;
  const int h = unit & 15, isK = unit >> 4;
  const size_t row = (size_t)blockIdx.x * 8 + rl;
  uint16_t* p = qkv + row * 3456 + isK * 1152 + h * 72;
  const float* w = isK ? kn : qn;
  float v[72];
#pragma unroll
  for (int i = 0; i < 9; i++) unpack8(((const uint4*)p)[i], v + i * 8);
  float ss = 0.f;
#pragma unroll
  for (int d = 0; d < 72; d++) ss += v[d] * v[d];
  const float rs = rsqrtf(ss * (1.f / 72.f) + 1e-6f);
#pragma unroll
  for (int d = 0; d < 72; d++) p[d] = f2b(v[d] * rs * w[d]);
}

// ---------------- spatial attention: 1 block = (bt,h), 1 thread = query l ----------------
__global__ __launch_bounds__(256) void attn_s_k(
    const uint16_t* __restrict__ qkv, uint16_t* __restrict__ out)
{
  const int bh = blockIdx.x;
  const int bt = bh >> 4, h = bh & 15;
  const int l = threadIdx.x;
  __shared__ __align__(16) uint16_t kb[128 * 72];
  __shared__ __align__(16) uint16_t vb[128 * 72];
  const size_t rowbase = (size_t)bt * 256;

  float q[72];
  {
    const uint16_t* qp = qkv + (rowbase + l) * 3456 + h * 72;
#pragma unroll
    for (int i = 0; i < 9; i++) unpack8(((const uint4*)qp)[i], q + i * 8);
  }
  float o[72];
#pragma unroll
  for (int d = 0; d < 72; d++) o[d] = 0.f;
  float mrun = -1e30f, lrun = 0.f;
  const float scale = 0.1178511301977579f;  // 1/sqrt(72)

  for (int c = 0; c < 2; c++) {
    __syncthreads();
    for (int idx = threadIdx.x; idx < 1152; idx += 256) {
      const int rr = idx / 9, cc = idx % 9;
      const size_t grow = rowbase + c * 128 + rr;
      ((uint4*)&kb[rr * 72])[cc] = *(const uint4*)(qkv + grow * 3456 + 1152 + h * 72 + cc * 8);
      ((uint4*)&vb[rr * 72])[cc] = *(const uint4*)(qkv + grow * 3456 + 2304 + h * 72 + cc * 8);
    }
    __syncthreads();
    for (int m = 0; m < 128; m++) {
      const uint4* kr = (const uint4*)&kb[m * 72];
      float s = 0.f;
#pragma unroll
      for (int i = 0; i < 9; i++) {
        float kf[8]; unpack8(kr[i], kf);
#pragma unroll
        for (int j = 0; j < 8; j++) s += q[i * 8 + j] * kf[j];
      }
      s *= scale;
      const float mnew = fmaxf(mrun, s);
      const float corr = __expf(mrun - mnew);
      const float p = __expf(s - mnew);
      lrun = lrun * corr + p;
      const uint4* vr = (const uint4*)&vb[m * 72];
#pragma unroll
      for (int i = 0; i < 9; i++) {
        float vf[8]; unpack8(vr[i], vf);
#pragma unroll
        for (int j = 0; j < 8; j++) o[i * 8 + j] = o[i * 8 + j] * corr + p * vf[j];
      }
      mrun = mnew;
    }
  }
  const float inv = 1.f / lrun;
  uint16_t* op = out + (rowbase + l) * 1152 + h * 72;
#pragma unroll
  for (int d = 0; d < 72; d++) op[d] = f2b(o[d] * inv);
}

// ---------------- temporal attention: 1 block = (b,l,head-group of 8), thread=(hh,tq) ----------------
__global__ __launch_bounds__(128) void attn_t_k(
    const uint16_t* __restrict__ qkv, uint16_t* __restrict__ out)
{
  const int blk = blockIdx.x;
  const int bl = blk >> 1, hg = blk & 1;
  const int b = bl >> 8, l = bl & 255;
  const int tid = threadIdx.x;
  const int hh = tid >> 4, tq = tid & 15;
  const int h = hg * 8 + hh;
  __shared__ __align__(16) uint16_t kb[8 * 16 * 72];
  __shared__ __align__(16) uint16_t vb[8 * 16 * 72];

#pragma unroll
  for (int it = 0; it < 9; it++) {
    const int idx = tid + it * 128;
    const int rowL = idx / 9, cc = idx % 9;
    const int hhL = rowL >> 4, tL = rowL & 15;
    const size_t grow = (size_t)b * 4096 + (size_t)tL * 256 + l;
    const int colk = 1152 + (hg * 8 + hhL) * 72 + cc * 8;
    ((uint4*)&kb[rowL * 72])[cc] = *(const uint4*)(qkv + grow * 3456 + colk);
    ((uint4*)&vb[rowL * 72])[cc] = *(const uint4*)(qkv + grow * 3456 + colk + 1152);
  }
  __syncthreads();

  float q[72];
  const size_t qrow = (size_t)b * 4096 + (size_t)tq * 256 + l;
  {
    const uint16_t* qp = qkv + qrow * 3456 + h * 72;
#pragma unroll
    for (int i = 0; i < 9; i++) unpack8(((const uint4*)qp)[i], q + i * 8);
  }
  const float scale = 0.1178511301977579f;
  float s[16];
#pragma unroll
  for (int m = 0; m < 16; m++) {
    const uint4* kr = (const uint4*)&kb[(hh * 16 + m) * 72];
    float a = 0.f;
#pragma unroll
    for (int i = 0; i < 9; i++) {
      float kf[8]; unpack8(kr[i], kf);
#pragma unroll
      for (int j = 0; j < 8; j++) a += q[i * 8 + j] * kf[j];
    }
    s[m] = a * scale;
  }
  float mx = -1e30f;
#pragma unroll
  for (int m = 0; m < 16; m++) mx = fmaxf(mx, s[m]);
  float sum = 0.f;
#pragma unroll
  for (int m = 0; m < 16; m++) { s[m] = __expf(s[m] - mx); sum += s[m]; }
  const float inv = 1.f / sum;
  float o[72];
#pragma unroll
  for (int d = 0; d < 72; d++) o[d] = 0.f;
#pragma unroll
  for (int m = 0; m < 16; m++) {
    const float p = s[m];
    const uint4* vr = (const uint4*)&vb[(hh * 16 + m) * 72];
#pragma unroll
    for (int i = 0; i < 9; i++) {
      float vf[8]; unpack8(vr[i], vf);
#pragma unroll
      for (int j = 0; j < 8; j++) o[i * 8 + j] += p * vf[j];
    }
  }
  uint16_t* op = out + qrow * 1152 + h * 72;
#pragma unroll
  for (int d = 0; d < 72; d++) op[d] = f2b(o[d] * inv);
}

// ---------------- transpose + fp32->bf16: in(KxN) -> out(NxK) ----------------
__global__ __launch_bounds__(256) void transcvt_k(
    const float* __restrict__ in, uint16_t* __restrict__ out, int K, int N)
{
  __shared__ float t[32][33];
  const int n0 = blockIdx.x * 32, k0 = blockIdx.y * 32;
  const int tx = threadIdx.x & 31, ty = threadIdx.x >> 5;
#pragma unroll
  for (int i = 0; i < 32; i += 8)
    t[ty + i][tx] = in[(size_t)(k0 + ty + i) * N + n0 + tx];
  __syncthreads();
#pragma unroll
  for (int i = 0; i < 32; i += 8)
    out[(size_t)(n0 + ty + i) * K + k0 + tx] = f2b(t[tx][ty + i]);
}

// ---------------- swiglu: h = silu(x1)*x2, 8 elems/thread ----------------
__global__ __launch_bounds__(256) void swiglu_k(
    const uint16_t* __restrict__ x1, const uint16_t* __restrict__ x2, uint16_t* __restrict__ h)
{
  const size_t i = ((size_t)blockIdx.x * 256 + threadIdx.x) * 8;
  float a[8], bb[8];
  unpack8(*(const uint4*)(x1 + i), a);
  unpack8(*(const uint4*)(x2 + i), bb);
  uint32_t r[4];
#pragma unroll
  for (int j = 0; j < 4; j++) {
    const float s0 = a[2 * j]     / (1.f + __expf(-a[2 * j]))     * bb[2 * j];
    const float s1 = a[2 * j + 1] / (1.f + __expf(-a[2 * j + 1])) * bb[2 * j + 1];
    r[j] = (uint32_t)f2b(s0) | ((uint32_t)f2b(s1) << 16);
  }
  *(uint4*)(h + i) = make_uint4(r[0], r[1], r[2], r[3]);
}

// ---------------- ada path ----------------
__global__ void siluc_k(const float* __restrict__ c, float* __restrict__ cs) {
  const int i = blockIdx.x * 256 + threadIdx.x;
  if (i < 2304) { const float v = c[i]; cs[i] = v / (1.f + __expf(-v)); }
}
__global__ __launch_bounds__(256) void ada_k(
    const float* __restrict__ cs, const float* __restrict__ W,
    const float* __restrict__ bias, float* __restrict__ chv)
{
  const int col = blockIdx.x * 256 + threadIdx.x;
  if (col >= 10368) return;
  float s0 = bias[col], s1 = bias[col];
  for (int k = 0; k < 1152; k++) {
    const float wv = W[(size_t)k * 10368 + col];
    s0 += cs[k] * wv;
    s1 += cs[1152 + k] * wv;
  }
  chv[col] = s0;
  chv[10368 + col] = s1;
}

extern "C" void kernel_launch(void* const* d_in, const int* in_sizes, int n_in,
                              void* d_out, int out_size, void* d_ws, size_t ws_size,
                              hipStream_t stream)
{
  const float* x_in    = (const float*)d_in[0];
  const float* c_in    = (const float*)d_in[1];
  const float* norm1w  = (const float*)d_in[2];
  const float* norm2w  = (const float*)d_in[3];
  const float* norm3w  = (const float*)d_in[4];
  const float* qn_s    = (const float*)d_in[5];
  const float* kn_s    = (const float*)d_in[6];
  const float* qkv_s_w = (const float*)d_in[7];
  const float* qkv_s_b = (const float*)d_in[8];
  const float* proj_s_w= (const float*)d_in[9];
  const float* proj_s_b= (const float*)d_in[10];
  const float* qn_t    = (const float*)d_in[11];
  const float* kn_t    = (const float*)d_in[12];
  const float* qkv_t_w = (const float*)d_in[13];
  const float* qkv_t_b = (const float*)d_in[14];
  const float* proj_t_w= (const float*)d_in[15];
  const float* proj_t_b= (const float*)d_in[16];
  const float* w12_w   = (const float*)d_in[17];
  const float* w12_b   = (const float*)d_in[18];
  const float* w3_w    = (const float*)d_in[19];
  const float* w3_b    = (const float*)d_in[20];
  const float* ada_w   = (const float*)d_in[21];
  const float* ada_b   = (const float*)d_in[22];

  float* X = (float*)d_out;  // fp32 residual accumulator; also final output

  char* wsb = (char*)d_ws; size_t off = 0;
  auto alloc = [&](size_t bytes) -> void* {
    void* p = wsb + off; off += bytes; off = (off + 255) & ~(size_t)255; return p;
  };
  uint16_t* XN    = (uint16_t*)alloc((size_t)8192 * 1152 * 2);  // xn / attn_out
  uint16_t* QKV   = (uint16_t*)alloc((size_t)8192 * 3456 * 2);  // qkv / x1 / h
  uint16_t* X2    = (uint16_t*)alloc((size_t)8192 * 3072 * 2);
  uint16_t* WqkvS = (uint16_t*)alloc((size_t)3456 * 1152 * 2);
  uint16_t* WprojS= (uint16_t*)alloc((size_t)1152 * 1152 * 2);
  uint16_t* WqkvT = (uint16_t*)alloc((size_t)3456 * 1152 * 2);
  uint16_t* WprojT= (uint16_t*)alloc((size_t)1152 * 1152 * 2);
  uint16_t* W12T  = (uint16_t*)alloc((size_t)6144 * 1152 * 2);
  uint16_t* W3T   = (uint16_t*)alloc((size_t)1152 * 3072 * 2);
  float* CH = (float*)alloc((size_t)2 * 10368 * 4);
  float* CS = (float*)alloc((size_t)2 * 1152 * 4);

  hipMemcpyAsync(X, x_in, (size_t)8192 * 1152 * 4, hipMemcpyDeviceToDevice, stream);
  siluc_k<<<9, 256, 0, stream>>>(c_in, CS);
  ada_k<<<41, 256, 0, stream>>>(CS, ada_w, ada_b, CH);

  transcvt_k<<<dim3(3456 / 32, 1152 / 32), 256, 0, stream>>>(qkv_s_w, WqkvS, 1152, 3456);
  transcvt_k<<<dim3(1152 / 32, 1152 / 32), 256, 0, stream>>>(proj_s_w, WprojS, 1152, 1152);
  transcvt_k<<<dim3(3456 / 32, 1152 / 32), 256, 0, stream>>>(qkv_t_w, WqkvT, 1152, 3456);
  transcvt_k<<<dim3(1152 / 32, 1152 / 32), 256, 0, stream>>>(proj_t_w, WprojT, 1152, 1152);
  transcvt_k<<<dim3(6144 / 32, 1152 / 32), 256, 0, stream>>>(w12_w, W12T, 1152, 6144);
  transcvt_k<<<dim3(1152 / 32, 3072 / 32), 256, 0, stream>>>(w3_w, W3T, 3072, 1152);

  // ---- spatial attention ----
  rmsnorm_k<<<8192, 256, 0, stream>>>(X, norm1w, CH, 0, 1, XN);
  gemm_k<<<dim3(27, 64), 256, 0, stream>>>(XN, WqkvS, qkv_s_b, QKV, nullptr, nullptr, nullptr,
                                           8192, 3456, 1152, 0);
  qknorm_k<<<1024, 256, 0, stream>>>(QKV, qn_s, kn_s);
  attn_s_k<<<512, 256, 0, stream>>>(QKV, XN);
  gemm_k<<<dim3(9, 64), 256, 0, stream>>>(XN, WprojS, proj_s_b, nullptr, X, X, CH + 2 * 1152,
                                          8192, 1152, 1152, 1);

  // ---- temporal attention ----
  rmsnorm_k<<<8192, 256, 0, stream>>>(X, norm2w, CH, 3, 4, XN);
  gemm_k<<<dim3(27, 64), 256, 0, stream>>>(XN, WqkvT, qkv_t_b, QKV, nullptr, nullptr, nullptr,
                                           8192, 3456, 1152, 0);
  qknorm_k<<<1024, 256, 0, stream>>>(QKV, qn_t, kn_t);
  attn_t_k<<<1024, 128, 0, stream>>>(QKV, XN);
  gemm_k<<<dim3(9, 64), 256, 0, stream>>>(XN, WprojT, proj_t_b, nullptr, X, X, CH + 5 * 1152,
                                          8192, 1152, 1152, 1);

  // ---- MLP ----
  rmsnorm_k<<<8192, 256, 0, stream>>>(X, norm3w, CH, 6, 7, XN);
  gemm_k<<<dim3(24, 64), 256, 0, stream>>>(XN, W12T, w12_b, QKV, nullptr, nullptr, nullptr,
                                           8192, 3072, 1152, 0);
  gemm_k<<<dim3(24, 64), 256, 0, stream>>>(XN, W12T + (size_t)3072 * 1152, w12_b + 3072, X2,
                                           nullptr, nullptr, nullptr, 8192, 3072, 1152, 0);
  swiglu_k<<<12288, 256, 0, stream>>>(QKV, X2, QKV);
  gemm_k<<<dim3(9, 64), 256, 0, stream>>>(QKV, W3T, w3_b, nullptr, X, X, CH + 8 * 1152,
                                          8192, 1152, 3072, 1);
}

// Round 2
// 1252.482 us; speedup vs baseline: 1.1740x; 1.1740x over previous
//
#include <hip/hip_runtime.h>
#include <stdint.h>

typedef __bf16 bf16x8 __attribute__((ext_vector_type(8)));
typedef float f32x4 __attribute__((ext_vector_type(4)));

__device__ __forceinline__ float b2f(uint32_t u) {
  union { uint32_t i; float f; } v; v.i = u << 16; return v.f;
}
__device__ __forceinline__ uint16_t f2b(float f) {
  union { float f; uint32_t i; } v; v.f = f;
  uint32_t r = (v.i + 0x7fffu + ((v.i >> 16) & 1u)) >> 16;
  return (uint16_t)r;
}
__device__ __forceinline__ void unpack8(uint4 u, float* f) {
  f[0] = b2f(u.x & 0xffffu); f[1] = b2f(u.x >> 16);
  f[2] = b2f(u.y & 0xffffu); f[3] = b2f(u.y >> 16);
  f[4] = b2f(u.z & 0xffffu); f[5] = b2f(u.z >> 16);
  f[6] = b2f(u.w & 0xffffu); f[7] = b2f(u.w >> 16);
}

__device__ __forceinline__ void gl2lds16(const void* g, void* l) {
  __builtin_amdgcn_global_load_lds(
      (const __attribute__((address_space(1))) void*)g,
      (__attribute__((address_space(3))) void*)l, 16, 0, 0);
}

// ---------------- Generic bf16 GEMM: C(MxN) = A(MxK) * Bt(NxK)^T ----------------
// m97-style: async global->LDS staging, 128x128 tile, 4 waves, 16x16x32 MFMA.
// mode 0: outb[r*N+c] = bf16(acc + bias[c])
// mode 1: outf[r*N+c] = resid[r*N+c] + gate[(r>>12)*10368 + c] * (acc + bias[c])
__global__ __launch_bounds__(256) void gemm_k(
    const uint16_t* __restrict__ A, const uint16_t* __restrict__ Bt,
    const float* __restrict__ bias,
    uint16_t* __restrict__ outb,
    float* __restrict__ outf, const float* __restrict__ resid,
    const float* __restrict__ gate,
    int M, int N, int K, int mode)
{
  __shared__ __align__(16) uint16_t As[128 * 32];
  __shared__ __align__(16) uint16_t Bs[128 * 32];
  const int tid = threadIdx.x;
  const int row0 = blockIdx.y * 128, col0 = blockIdx.x * 128;
  const int lane = tid & 63, wave = tid >> 6;
  const int l15 = lane & 15, quad = lane >> 4;
  const int wm = (wave & 1) * 64, wn = (wave >> 1) * 64;

  f32x4 acc[4][4];
  const f32x4 zero = {0.f, 0.f, 0.f, 0.f};
  for (int i = 0; i < 4; i++)
    for (int j = 0; j < 4; j++)
      acc[i][j] = zero;

  // async staging geometry: wave covers rows [wave*32, wave*32+32) of the tile,
  // in two 16-row segments; lane -> (row = seg*16 + lane>>2, 16B chunk = lane&3)
  const int rseg = wave * 32 + (lane >> 2);
  const int kseg8 = (lane & 3) * 8;
  const uint16_t* gA = A + (size_t)(row0 + rseg) * K + kseg8;
  const uint16_t* gB = Bt + (size_t)(col0 + rseg) * K + kseg8;
  char* ldsA = (char*)As + wave * 2048;
  char* ldsB = (char*)Bs + wave * 2048;
  const size_t rowK16 = (size_t)16 * K;

  for (int k0 = 0; k0 < K; k0 += 32) {
    __syncthreads();
    gl2lds16(gA + k0,          ldsA);
    gl2lds16(gA + rowK16 + k0, ldsA + 1024);
    gl2lds16(gB + k0,          ldsB);
    gl2lds16(gB + rowK16 + k0, ldsB + 1024);
    __syncthreads();

    bf16x8 af[4], bfr[4];
#pragma unroll
    for (int i = 0; i < 4; i++) {
      af[i]  = *(const bf16x8*)&As[(wm + i * 16 + l15) * 32 + quad * 8];
      bfr[i] = *(const bf16x8*)&Bs[(wn + i * 16 + l15) * 32 + quad * 8];
    }
#pragma unroll
    for (int mi = 0; mi < 4; mi++)
#pragma unroll
      for (int ni = 0; ni < 4; ni++)
        acc[mi][ni] = __builtin_amdgcn_mfma_f32_16x16x32_bf16(af[mi], bfr[ni], acc[mi][ni], 0, 0, 0);
  }

#pragma unroll
  for (int mi = 0; mi < 4; mi++) {
#pragma unroll
    for (int ni = 0; ni < 4; ni++) {
      const int colg = col0 + wn + ni * 16 + l15;
      const float bv = bias ? bias[colg] : 0.f;
#pragma unroll
      for (int i = 0; i < 4; i++) {
        const int rowg = row0 + wm + mi * 16 + quad * 4 + i;
        const float v = acc[mi][ni][i] + bv;
        const size_t idx = (size_t)rowg * N + colg;
        if (mode == 0) {
          outb[idx] = f2b(v);
        } else {
          const int b = rowg >> 12;  // T*L = 4096 rows per batch
          outf[idx] = resid[idx] + gate[b * 10368 + colg] * v;
        }
      }
    }
  }
}

// ---------------- RMS + adaLN modulate ----------------
__global__ __launch_bounds__(256) void rmsnorm_k(
    const float* __restrict__ x, const float* __restrict__ w,
    const float* __restrict__ chv, int shsel, int scsel,
    uint16_t* __restrict__ xn)
{
  const int row = blockIdx.x;
  const int b = row >> 12;
  const float* xr = x + (size_t)row * 1152;
  float ss = 0.f;
  for (int d = threadIdx.x; d < 1152; d += 256) { const float v = xr[d]; ss += v * v; }
  for (int off = 32; off > 0; off >>= 1) ss += __shfl_down(ss, off);
  __shared__ float red[4];
  if ((threadIdx.x & 63) == 0) red[threadIdx.x >> 6] = ss;
  __syncthreads();
  const float tot = red[0] + red[1] + red[2] + red[3];
  const float rs = rsqrtf(tot * (1.f / 1152.f) + 1e-6f);
  const float* sh = chv + b * 10368 + shsel * 1152;
  const float* sc = chv + b * 10368 + scsel * 1152;
  uint16_t* xo = xn + (size_t)row * 1152;
  for (int d = threadIdx.x; d < 1152; d += 256)
    xo[d] = f2b(xr[d] * rs * w[d] * (1.f + sc[d]) + sh[d]);
}

// ---------------- per-head RMS norm of q,k in qkv (in place) ----------------
__global__ __launch_bounds__(256) void qknorm_k(
    uint16_t* __restrict__ qkv, const float* __restrict__ qn, const float* __restrict__ kn)
{
  const int tid = threadIdx.x;
  const int rl = tid >> 5, unit = tid & 31;
  const int h = unit & 15, isK = unit >> 4;
  const size_t row = (size_t)blockIdx.x * 8 + rl;
  uint16_t* p = qkv + row * 3456 + isK * 1152 + h * 72;
  const float* w = isK ? kn : qn;
  float v[72];
#pragma unroll
  for (int i = 0; i < 9; i++) unpack8(((const uint4*)p)[i], v + i * 8);
  float ss = 0.f;
#pragma unroll
  for (int d = 0; d < 72; d++) ss += v[d] * v[d];
  const float rs = rsqrtf(ss * (1.f / 72.f) + 1e-6f);
#pragma unroll
  for (int d = 0; d < 72; d++) p[d] = f2b(v[d] * rs * w[d]);
}

// ---------------- spatial attention, MFMA flash: block=(bt,h), 4 waves x 64 queries ----------------
#define AK_STRIDE 104
#define VT_STRIDE 88
#define PS_STRIDE 72
__global__ __launch_bounds__(256) void attn_s_k(
    const uint16_t* __restrict__ qkv, uint16_t* __restrict__ out)
{
  __shared__ __align__(16) uint16_t Ks[64 * AK_STRIDE];      // 13312 B, rows=key, cols=dim
  __shared__ __align__(16) uint16_t Vt[80 * VT_STRIDE];      // 14080 B, rows=dim, cols=key
  __shared__ __align__(16) uint16_t Ps[4 * 64 * PS_STRIDE];  // 36864 B, per-wave P
  const int bh = blockIdx.x;
  const int bt = bh >> 4, h = bh & 15;
  const int tid = threadIdx.x;
  const int lane = tid & 63, wave = tid >> 6;
  const int l15 = lane & 15, quad = lane >> 4;
  const size_t rowbase = (size_t)bt * 256;
  const float scale = 0.1178511301977579f;  // 1/sqrt(72)

  union { uint4 u; bf16x8 v; } zu; zu.u = make_uint4(0, 0, 0, 0);
  const bf16x8 zero8 = zu.v;

  // Q fragments: A[m=l15][k=quad*8+j], rows wave*64+mi*16+l15, D=72 padded to 96
  bf16x8 qf[4][3];
#pragma unroll
  for (int mi = 0; mi < 4; mi++) {
    const uint16_t* qp = qkv + (rowbase + wave * 64 + mi * 16 + l15) * 3456 + h * 72;
    qf[mi][0] = *(const bf16x8*)(qp + quad * 8);
    qf[mi][1] = *(const bf16x8*)(qp + 32 + quad * 8);
    qf[mi][2] = (quad == 0) ? *(const bf16x8*)(qp + 64) : zero8;
  }

  f32x4 oacc[4][5];
#pragma unroll
  for (int mi = 0; mi < 4; mi++)
#pragma unroll
    for (int dt = 0; dt < 5; dt++)
      oacc[mi][dt] = (f32x4){0.f, 0.f, 0.f, 0.f};
  float mrun[4][4], lrun[4][4];
#pragma unroll
  for (int mi = 0; mi < 4; mi++)
#pragma unroll
    for (int i = 0; i < 4; i++) { mrun[mi][i] = -1e30f; lrun[mi][i] = 0.f; }

  uint16_t* psw = &Ps[wave * 64 * PS_STRIDE];

  for (int c = 0; c < 4; c++) {
    __syncthreads();
    // stage K (row-major) and V^T; 576 uint4 chunks, 9 consecutive chunks = one 144B row
    for (int idx = tid; idx < 576; idx += 256) {
      const int rr = idx / 9, cc = idx - rr * 9;
      const uint16_t* kg = qkv + (rowbase + c * 64 + rr) * 3456 + 1152 + h * 72 + cc * 8;
      *(uint4*)&Ks[rr * AK_STRIDE + cc * 8] = *(const uint4*)kg;
      uint4 vv = *(const uint4*)(kg + 1152);
      const uint16_t* e = (const uint16_t*)&vv;
#pragma unroll
      for (int j = 0; j < 8; j++) Vt[(cc * 8 + j) * VT_STRIDE + rr] = e[j];
    }
    __syncthreads();

    // S = Q K^T  (rows=query in C-layout, cols=key)
    f32x4 s[4][4];
#pragma unroll
    for (int mi = 0; mi < 4; mi++)
#pragma unroll
      for (int ni = 0; ni < 4; ni++)
        s[mi][ni] = (f32x4){0.f, 0.f, 0.f, 0.f};
#pragma unroll
    for (int ni = 0; ni < 4; ni++) {
      bf16x8 kf0 = *(const bf16x8*)&Ks[(ni * 16 + l15) * AK_STRIDE + quad * 8];
      bf16x8 kf1 = *(const bf16x8*)&Ks[(ni * 16 + l15) * AK_STRIDE + 32 + quad * 8];
      bf16x8 kf2 = (quad == 0) ? *(const bf16x8*)&Ks[(ni * 16 + l15) * AK_STRIDE + 64] : zero8;
#pragma unroll
      for (int mi = 0; mi < 4; mi++) {
        s[mi][ni] = __builtin_amdgcn_mfma_f32_16x16x32_bf16(qf[mi][0], kf0, s[mi][ni], 0, 0, 0);
        s[mi][ni] = __builtin_amdgcn_mfma_f32_16x16x32_bf16(qf[mi][1], kf1, s[mi][ni], 0, 0, 0);
        s[mi][ni] = __builtin_amdgcn_mfma_f32_16x16x32_bf16(qf[mi][2], kf2, s[mi][ni], 0, 0, 0);
      }
    }

    // online softmax per row (row = mi*16 + quad*4 + i, spread over 16 l15 lanes x 4 ni)
#pragma unroll
    for (int mi = 0; mi < 4; mi++) {
#pragma unroll
      for (int i = 0; i < 4; i++) {
        float mx = fmaxf(fmaxf(s[mi][0][i], s[mi][1][i]), fmaxf(s[mi][2][i], s[mi][3][i])) * scale;
#pragma unroll
        for (int d = 1; d < 16; d <<= 1) mx = fmaxf(mx, __shfl_xor(mx, d));
        const float mnew = fmaxf(mrun[mi][i], mx);
        const float corr = __expf(mrun[mi][i] - mnew);
        mrun[mi][i] = mnew;
        float psum = 0.f;
#pragma unroll
        for (int ni = 0; ni < 4; ni++) {
          const float p = __expf(s[mi][ni][i] * scale - mnew);
          s[mi][ni][i] = p;
          psum += p;
        }
#pragma unroll
        for (int d = 1; d < 16; d <<= 1) psum += __shfl_xor(psum, d);
        lrun[mi][i] = lrun[mi][i] * corr + psum;
#pragma unroll
        for (int dt = 0; dt < 5; dt++) oacc[mi][dt][i] *= corr;
      }
    }

    // P -> per-wave LDS (A-operand staging)
#pragma unroll
    for (int mi = 0; mi < 4; mi++)
#pragma unroll
      for (int ni = 0; ni < 4; ni++)
#pragma unroll
        for (int i = 0; i < 4; i++)
          psw[(mi * 16 + quad * 4 + i) * PS_STRIDE + ni * 16 + l15] = f2b(s[mi][ni][i]);

    // O += P V   (A = P[m=query][k=key], B = Vt[n=dim][k=key])
#pragma unroll
    for (int kk = 0; kk < 2; kk++) {
      bf16x8 pf[4];
#pragma unroll
      for (int mi = 0; mi < 4; mi++)
        pf[mi] = *(const bf16x8*)&psw[(mi * 16 + l15) * PS_STRIDE + kk * 32 + quad * 8];
#pragma unroll
      for (int dt = 0; dt < 5; dt++) {
        bf16x8 vf = *(const bf16x8*)&Vt[(dt * 16 + l15) * VT_STRIDE + kk * 32 + quad * 8];
#pragma unroll
        for (int mi = 0; mi < 4; mi++)
          oacc[mi][dt] = __builtin_amdgcn_mfma_f32_16x16x32_bf16(pf[mi], vf, oacc[mi][dt], 0, 0, 0);
      }
    }
  }

  // epilogue
#pragma unroll
  for (int mi = 0; mi < 4; mi++) {
#pragma unroll
    for (int i = 0; i < 4; i++) {
      const float inv = 1.f / lrun[mi][i];
      const size_t orow = rowbase + wave * 64 + mi * 16 + quad * 4 + i;
#pragma unroll
      for (int dt = 0; dt < 5; dt++) {
        const int d = dt * 16 + l15;
        if (d < 72) out[orow * 1152 + h * 72 + d] = f2b(oacc[mi][dt][i] * inv);
      }
    }
  }
}

// ---------------- temporal attention (T=16): scalar, small FLOPs ----------------
__global__ __launch_bounds__(128) void attn_t_k(
    const uint16_t* __restrict__ qkv, uint16_t* __restrict__ out)
{
  const int blk = blockIdx.x;
  const int bl = blk >> 1, hg = blk & 1;
  const int b = bl >> 8, l = bl & 255;
  const int tid = threadIdx.x;
  const int hh = tid >> 4, tq = tid & 15;
  const int h = hg * 8 + hh;
  __shared__ __align__(16) uint16_t kb[8 * 16 * 72];
  __shared__ __align__(16) uint16_t vb[8 * 16 * 72];

#pragma unroll
  for (int it = 0; it < 9; it++) {
    const int idx = tid + it * 128;
    const int rowL = idx / 9, cc = idx % 9;
    const int hhL = rowL >> 4, tL = rowL & 15;
    const size_t grow = (size_t)b * 4096 + (size_t)tL * 256 + l;
    const int colk = 1152 + (hg * 8 + hhL) * 72 + cc * 8;
    ((uint4*)&kb[rowL * 72])[cc] = *(const uint4*)(qkv + grow * 3456 + colk);
    ((uint4*)&vb[rowL * 72])[cc] = *(const uint4*)(qkv + grow * 3456 + colk + 1152);
  }
  __syncthreads();

  float q[72];
  const size_t qrow = (size_t)b * 4096 + (size_t)tq * 256 + l;
  {
    const uint16_t* qp = qkv + qrow * 3456 + h * 72;
#pragma unroll
    for (int i = 0; i < 9; i++) unpack8(((const uint4*)qp)[i], q + i * 8);
  }
  const float scale = 0.1178511301977579f;
  float s[16];
#pragma unroll
  for (int m = 0; m < 16; m++) {
    const uint4* kr = (const uint4*)&kb[(hh * 16 + m) * 72];
    float a = 0.f;
#pragma unroll
    for (int i = 0; i < 9; i++) {
      float kf[8]; unpack8(kr[i], kf);
#pragma unroll
      for (int j = 0; j < 8; j++) a += q[i * 8 + j] * kf[j];
    }
    s[m] = a * scale;
  }
  float mx = -1e30f;
#pragma unroll
  for (int m = 0; m < 16; m++) mx = fmaxf(mx, s[m]);
  float sum = 0.f;
#pragma unroll
  for (int m = 0; m < 16; m++) { s[m] = __expf(s[m] - mx); sum += s[m]; }
  const float inv = 1.f / sum;
  float o[72];
#pragma unroll
  for (int d = 0; d < 72; d++) o[d] = 0.f;
#pragma unroll
  for (int m = 0; m < 16; m++) {
    const float p = s[m];
    const uint4* vr = (const uint4*)&vb[(hh * 16 + m) * 72];
#pragma unroll
    for (int i = 0; i < 9; i++) {
      float vf[8]; unpack8(vr[i], vf);
#pragma unroll
      for (int j = 0; j < 8; j++) o[i * 8 + j] += p * vf[j];
    }
  }
  uint16_t* op = out + qrow * 1152 + h * 72;
#pragma unroll
  for (int d = 0; d < 72; d++) op[d] = f2b(o[d] * inv);
}

// ---------------- transpose + fp32->bf16: in(KxN) -> out(NxK) ----------------
__global__ __launch_bounds__(256) void transcvt_k(
    const float* __restrict__ in, uint16_t* __restrict__ out, int K, int N)
{
  __shared__ float t[32][33];
  const int n0 = blockIdx.x * 32, k0 = blockIdx.y * 32;
  const int tx = threadIdx.x & 31, ty = threadIdx.x >> 5;
#pragma unroll
  for (int i = 0; i < 32; i += 8)
    t[ty + i][tx] = in[(size_t)(k0 + ty + i) * N + n0 + tx];
  __syncthreads();
#pragma unroll
  for (int i = 0; i < 32; i += 8)
    out[(size_t)(n0 + ty + i) * K + k0 + tx] = f2b(t[tx][ty + i]);
}

// ---------------- swiglu ----------------
__global__ __launch_bounds__(256) void swiglu_k(
    const uint16_t* __restrict__ x1, const uint16_t* __restrict__ x2, uint16_t* __restrict__ h)
{
  const size_t i = ((size_t)blockIdx.x * 256 + threadIdx.x) * 8;
  float a[8], bb[8];
  unpack8(*(const uint4*)(x1 + i), a);
  unpack8(*(const uint4*)(x2 + i), bb);
  uint32_t r[4];
#pragma unroll
  for (int j = 0; j < 4; j++) {
    const float s0 = a[2 * j]     / (1.f + __expf(-a[2 * j]))     * bb[2 * j];
    const float s1 = a[2 * j + 1] / (1.f + __expf(-a[2 * j + 1])) * bb[2 * j + 1];
    r[j] = (uint32_t)f2b(s0) | ((uint32_t)f2b(s1) << 16);
  }
  *(uint4*)(h + i) = make_uint4(r[0], r[1], r[2], r[3]);
}

// ---------------- ada path ----------------
__global__ void siluc_k(const float* __restrict__ c, float* __restrict__ cs) {
  const int i = blockIdx.x * 256 + threadIdx.x;
  if (i < 2304) { const float v = c[i]; cs[i] = v / (1.f + __expf(-v)); }
}
__global__ __launch_bounds__(256) void ada_k(
    const float* __restrict__ cs, const float* __restrict__ W,
    const float* __restrict__ bias, float* __restrict__ chv)
{
  const int col = blockIdx.x * 256 + threadIdx.x;
  if (col >= 10368) return;
  float s0 = bias[col], s1 = bias[col];
  for (int k = 0; k < 1152; k++) {
    const float wv = W[(size_t)k * 10368 + col];
    s0 += cs[k] * wv;
    s1 += cs[1152 + k] * wv;
  }
  chv[col] = s0;
  chv[10368 + col] = s1;
}

extern "C" void kernel_launch(void* const* d_in, const int* in_sizes, int n_in,
                              void* d_out, int out_size, void* d_ws, size_t ws_size,
                              hipStream_t stream)
{
  const float* c_in    = (const float*)d_in[1];
  const float* norm1w  = (const float*)d_in[2];
  const float* norm2w  = (const float*)d_in[3];
  const float* norm3w  = (const float*)d_in[4];
  const float* qn_s    = (const float*)d_in[5];
  const float* kn_s    = (const float*)d_in[6];
  const float* qkv_s_w = (const float*)d_in[7];
  const float* qkv_s_b = (const float*)d_in[8];
  const float* proj_s_w= (const float*)d_in[9];
  const float* proj_s_b= (const float*)d_in[10];
  const float* qn_t    = (const float*)d_in[11];
  const float* kn_t    = (const float*)d_in[12];
  const float* qkv_t_w = (const float*)d_in[13];
  const float* qkv_t_b = (const float*)d_in[14];
  const float* proj_t_w= (const float*)d_in[15];
  const float* proj_t_b= (const float*)d_in[16];
  const float* w12_w   = (const float*)d_in[17];
  const float* w12_b   = (const float*)d_in[18];
  const float* w3_w    = (const float*)d_in[19];
  const float* w3_b    = (const float*)d_in[20];
  const float* ada_w   = (const float*)d_in[21];
  const float* ada_b   = (const float*)d_in[22];

  float* X = (float*)d_out;  // fp32 residual accumulator; also final output

  char* wsb = (char*)d_ws; size_t off = 0;
  auto alloc = [&](size_t bytes) -> void* {
    void* p = wsb + off; off += bytes; off = (off + 255) & ~(size_t)255; return p;
  };
  uint16_t* XN    = (uint16_t*)alloc((size_t)8192 * 1152 * 2);  // xn / attn_out
  uint16_t* QKV   = (uint16_t*)alloc((size_t)8192 * 3456 * 2);  // qkv / x1 / h
  uint16_t* X2    = (uint16_t*)alloc((size_t)8192 * 3072 * 2);
  uint16_t* WqkvS = (uint16_t*)alloc((size_t)3456 * 1152 * 2);
  uint16_t* WprojS= (uint16_t*)alloc((size_t)1152 * 1152 * 2);
  uint16_t* WqkvT = (uint16_t*)alloc((size_t)3456 * 1152 * 2);
  uint16_t* WprojT= (uint16_t*)alloc((size_t)1152 * 1152 * 2);
  uint16_t* W12T  = (uint16_t*)alloc((size_t)6144 * 1152 * 2);
  uint16_t* W3T   = (uint16_t*)alloc((size_t)1152 * 3072 * 2);
  float* CH = (float*)alloc((size_t)2 * 10368 * 4);
  float* CS = (float*)alloc((size_t)2 * 1152 * 4);

  hipMemcpyAsync(X, d_in[0], (size_t)8192 * 1152 * 4, hipMemcpyDeviceToDevice, stream);
  siluc_k<<<9, 256, 0, stream>>>(c_in, CS);
  ada_k<<<41, 256, 0, stream>>>(CS, ada_w, ada_b, CH);

  transcvt_k<<<dim3(3456 / 32, 1152 / 32), 256, 0, stream>>>(qkv_s_w, WqkvS, 1152, 3456);
  transcvt_k<<<dim3(1152 / 32, 1152 / 32), 256, 0, stream>>>(proj_s_w, WprojS, 1152, 1152);
  transcvt_k<<<dim3(3456 / 32, 1152 / 32), 256, 0, stream>>>(qkv_t_w, WqkvT, 1152, 3456);
  transcvt_k<<<dim3(1152 / 32, 1152 / 32), 256, 0, stream>>>(proj_t_w, WprojT, 1152, 1152);
  transcvt_k<<<dim3(6144 / 32, 1152 / 32), 256, 0, stream>>>(w12_w, W12T, 1152, 6144);
  transcvt_k<<<dim3(1152 / 32, 3072 / 32), 256, 0, stream>>>(w3_w, W3T, 3072, 1152);

  // ---- spatial attention ----
  rmsnorm_k<<<8192, 256, 0, stream>>>(X, norm1w, CH, 0, 1, XN);
  gemm_k<<<dim3(27, 64), 256, 0, stream>>>(XN, WqkvS, qkv_s_b, QKV, nullptr, nullptr, nullptr,
                                           8192, 3456, 1152, 0);
  qknorm_k<<<1024, 256, 0, stream>>>(QKV, qn_s, kn_s);
  attn_s_k<<<512, 256, 0, stream>>>(QKV, XN);
  gemm_k<<<dim3(9, 64), 256, 0, stream>>>(XN, WprojS, proj_s_b, nullptr, X, X, CH + 2 * 1152,
                                          8192, 1152, 1152, 1);

  // ---- temporal attention ----
  rmsnorm_k<<<8192, 256, 0, stream>>>(X, norm2w, CH, 3, 4, XN);
  gemm_k<<<dim3(27, 64), 256, 0, stream>>>(XN, WqkvT, qkv_t_b, QKV, nullptr, nullptr, nullptr,
                                           8192, 3456, 1152, 0);
  qknorm_k<<<1024, 256, 0, stream>>>(QKV, qn_t, kn_t);
  attn_t_k<<<1024, 128, 0, stream>>>(QKV, XN);
  gemm_k<<<dim3(9, 64), 256, 0, stream>>>(XN, WprojT, proj_t_b, nullptr, X, X, CH + 5 * 1152,
                                          8192, 1152, 1152, 1);

  // ---- MLP ----
  rmsnorm_k<<<8192, 256, 0, stream>>>(X, norm3w, CH, 6, 7, XN);
  gemm_k<<<dim3(24, 64), 256, 0, stream>>>(XN, W12T, w12_b, QKV, nullptr, nullptr, nullptr,
                                           8192, 3072, 1152, 0);
  gemm_k<<<dim3(24, 64), 256, 0, stream>>>(XN, W12T + (size_t)3072 * 1152, w12_b + 3072, X2,
                                           nullptr, nullptr, nullptr, 8192, 3072, 1152, 0);
  swiglu_k<<<12288, 256, 0, stream>>>(QKV, X2, QKV);
  gemm_k<<<dim3(9, 64), 256, 0, stream>>>(QKV, W3T, w3_b, nullptr, X, X, CH + 8 * 1152,
                                          8192, 1152, 3072, 1);
}

// Round 3
// 1183.834 us; speedup vs baseline: 1.2421x; 1.0580x over previous
//
#include <hip/hip_runtime.h>
#include <stdint.h>

typedef __bf16 bf16x8 __attribute__((ext_vector_type(8)));
typedef float f32x4 __attribute__((ext_vector_type(4)));

__device__ __forceinline__ float b2f(uint32_t u) {
  union { uint32_t i; float f; } v; v.i = u << 16; return v.f;
}
__device__ __forceinline__ uint16_t f2b(float f) {
  union { float f; uint32_t i; } v; v.f = f;
  uint32_t r = (v.i + 0x7fffu + ((v.i >> 16) & 1u)) >> 16;
  return (uint16_t)r;
}
__device__ __forceinline__ void unpack8(uint4 u, float* f) {
  f[0] = b2f(u.x & 0xffffu); f[1] = b2f(u.x >> 16);
  f[2] = b2f(u.y & 0xffffu); f[3] = b2f(u.y >> 16);
  f[4] = b2f(u.z & 0xffffu); f[5] = b2f(u.z >> 16);
  f[6] = b2f(u.w & 0xffffu); f[7] = b2f(u.w >> 16);
}

__device__ __forceinline__ void gl2lds16(const void* g, void* l) {
  __builtin_amdgcn_global_load_lds(
      (const __attribute__((address_space(1))) void*)g,
      (__attribute__((address_space(3))) void*)l, 16, 0, 0);
}

// ---------------- Generic bf16 GEMM: C(MxN) = A(MxK) * Bt(NxK)^T ----------------
// 1-D grid = mtiles*ntiles, grouped swizzle (panels of 8 M-tiles, N fastest) for
// L2 locality; double-buffered async global->LDS staging, single barrier/K-step.
// mode 0: outb[r*N+c] = bf16(acc + bias[c])
// mode 1: outf[r*N+c] = resid[r*N+c] + gate[(r>>12)*10368 + c] * (acc + bias[c])
__global__ __launch_bounds__(256) void gemm_k(
    const uint16_t* __restrict__ A, const uint16_t* __restrict__ Bt,
    const float* __restrict__ bias,
    uint16_t* __restrict__ outb,
    float* __restrict__ outf, const float* __restrict__ resid,
    const float* __restrict__ gate,
    int N, int K, int mode)
{
  __shared__ __align__(16) uint16_t As[2][128 * 32];
  __shared__ __align__(16) uint16_t Bs[2][128 * 32];
  const int tid = threadIdx.x;
  const int ntiles = N >> 7;
  // grouped swizzle: panel of 8 m-tiles; within panel, n varies fastest
  const int panel_sz = ntiles * 8;
  const int panel = blockIdx.x / panel_sz;
  const int rr_ = blockIdx.x - panel * panel_sz;
  const int mt_in = rr_ / ntiles;
  const int nt = rr_ - mt_in * ntiles;
  const int row0 = (panel * 8 + mt_in) * 128, col0 = nt * 128;

  const int lane = tid & 63, wave = tid >> 6;
  const int l15 = lane & 15, quad = lane >> 4;
  const int wm = (wave & 1) * 64, wn = (wave >> 1) * 64;

  f32x4 acc[4][4];
  const f32x4 zero = {0.f, 0.f, 0.f, 0.f};
  for (int i = 0; i < 4; i++)
    for (int j = 0; j < 4; j++)
      acc[i][j] = zero;

  // staging: wave covers tile rows [wave*32, wave*32+32), two 16-row segments;
  // lane -> (row = seg*16 + lane>>2, 16B chunk = lane&3)
  const int rseg = wave * 32 + (lane >> 2);
  const int kseg8 = (lane & 3) * 8;
  const uint16_t* gA = A + (size_t)(row0 + rseg) * K + kseg8;
  const uint16_t* gB = Bt + (size_t)(col0 + rseg) * K + kseg8;
  const size_t rowK16 = (size_t)16 * K;
  const int woff = wave * 2048;

  // prologue: stage k0=0 into buffer 0
  gl2lds16(gA,          (char*)As[0] + woff);
  gl2lds16(gA + rowK16, (char*)As[0] + woff + 1024);
  gl2lds16(gB,          (char*)Bs[0] + woff);
  gl2lds16(gB + rowK16, (char*)Bs[0] + woff + 1024);

  for (int k0 = 0; k0 < K; k0 += 32) {
    const int cur = (k0 >> 5) & 1;
    __syncthreads();  // drains prefetch issued one iteration ago (full overlap)
    if (k0 + 32 < K) {
      const int nxt = cur ^ 1;
      gl2lds16(gA + k0 + 32,          (char*)As[nxt] + woff);
      gl2lds16(gA + rowK16 + k0 + 32, (char*)As[nxt] + woff + 1024);
      gl2lds16(gB + k0 + 32,          (char*)Bs[nxt] + woff);
      gl2lds16(gB + rowK16 + k0 + 32, (char*)Bs[nxt] + woff + 1024);
    }

    bf16x8 af[4], bfr[4];
#pragma unroll
    for (int i = 0; i < 4; i++) {
      af[i]  = *(const bf16x8*)&As[cur][(wm + i * 16 + l15) * 32 + quad * 8];
      bfr[i] = *(const bf16x8*)&Bs[cur][(wn + i * 16 + l15) * 32 + quad * 8];
    }
#pragma unroll
    for (int mi = 0; mi < 4; mi++)
#pragma unroll
      for (int ni = 0; ni < 4; ni++)
        acc[mi][ni] = __builtin_amdgcn_mfma_f32_16x16x32_bf16(af[mi], bfr[ni], acc[mi][ni], 0, 0, 0);
  }

#pragma unroll
  for (int mi = 0; mi < 4; mi++) {
#pragma unroll
    for (int ni = 0; ni < 4; ni++) {
      const int colg = col0 + wn + ni * 16 + l15;
      const float bv = bias ? bias[colg] : 0.f;
#pragma unroll
      for (int i = 0; i < 4; i++) {
        const int rowg = row0 + wm + mi * 16 + quad * 4 + i;
        const float v = acc[mi][ni][i] + bv;
        const size_t idx = (size_t)rowg * N + colg;
        if (mode == 0) {
          outb[idx] = f2b(v);
        } else {
          const int b = rowg >> 12;  // T*L = 4096 rows per batch
          outf[idx] = resid[idx] + gate[b * 10368 + colg] * v;
        }
      }
    }
  }
}

// ---------------- RMS + adaLN modulate ----------------
__global__ __launch_bounds__(256) void rmsnorm_k(
    const float* __restrict__ x, const float* __restrict__ w,
    const float* __restrict__ chv, int shsel, int scsel,
    uint16_t* __restrict__ xn)
{
  const int row = blockIdx.x;
  const int b = row >> 12;
  const float* xr = x + (size_t)row * 1152;
  float ss = 0.f;
  for (int d = threadIdx.x; d < 1152; d += 256) { const float v = xr[d]; ss += v * v; }
  for (int off = 32; off > 0; off >>= 1) ss += __shfl_down(ss, off);
  __shared__ float red[4];
  if ((threadIdx.x & 63) == 0) red[threadIdx.x >> 6] = ss;
  __syncthreads();
  const float tot = red[0] + red[1] + red[2] + red[3];
  const float rs = rsqrtf(tot * (1.f / 1152.f) + 1e-6f);
  const float* sh = chv + b * 10368 + shsel * 1152;
  const float* sc = chv + b * 10368 + scsel * 1152;
  uint16_t* xo = xn + (size_t)row * 1152;
  for (int d = threadIdx.x; d < 1152; d += 256)
    xo[d] = f2b(xr[d] * rs * w[d] * (1.f + sc[d]) + sh[d]);
}

// ---------------- per-head RMS norm of q,k in qkv (in place) ----------------
__global__ __launch_bounds__(256) void qknorm_k(
    uint16_t* __restrict__ qkv, const float* __restrict__ qn, const float* __restrict__ kn)
{
  const int tid = threadIdx.x;
  const int rl = tid >> 5, unit = tid & 31;
  const int h = unit & 15, isK = unit >> 4;
  const size_t row = (size_t)blockIdx.x * 8 + rl;
  uint16_t* p = qkv + row * 3456 + isK * 1152 + h * 72;
  const float* w = isK ? kn : qn;
  float v[72];
#pragma unroll
  for (int i = 0; i < 9; i++) unpack8(((const uint4*)p)[i], v + i * 8);
  float ss = 0.f;
#pragma unroll
  for (int d = 0; d < 72; d++) ss += v[d] * v[d];
  const float rs = rsqrtf(ss * (1.f / 72.f) + 1e-6f);
#pragma unroll
  for (int d = 0; d < 72; d++) p[d] = f2b(v[d] * rs * w[d]);
}

// ---------------- spatial attention, MFMA flash: block=(bt,h), 4 waves x 64 queries ----------------
#define AK_STRIDE 104
#define VT_STRIDE 88
#define PS_STRIDE 72
__global__ __launch_bounds__(256) void attn_s_k(
    const uint16_t* __restrict__ qkv, uint16_t* __restrict__ out)
{
  __shared__ __align__(16) uint16_t Ks[64 * AK_STRIDE];
  __shared__ __align__(16) uint16_t Vt[80 * VT_STRIDE];
  __shared__ __align__(16) uint16_t Ps[4 * 64 * PS_STRIDE];
  const int bh = blockIdx.x;
  const int bt = bh >> 4, h = bh & 15;
  const int tid = threadIdx.x;
  const int lane = tid & 63, wave = tid >> 6;
  const int l15 = lane & 15, quad = lane >> 4;
  const size_t rowbase = (size_t)bt * 256;
  const float scale = 0.1178511301977579f;  // 1/sqrt(72)

  union { uint4 u; bf16x8 v; } zu; zu.u = make_uint4(0, 0, 0, 0);
  const bf16x8 zero8 = zu.v;

  bf16x8 qf[4][3];
#pragma unroll
  for (int mi = 0; mi < 4; mi++) {
    const uint16_t* qp = qkv + (rowbase + wave * 64 + mi * 16 + l15) * 3456 + h * 72;
    qf[mi][0] = *(const bf16x8*)(qp + quad * 8);
    qf[mi][1] = *(const bf16x8*)(qp + 32 + quad * 8);
    qf[mi][2] = (quad == 0) ? *(const bf16x8*)(qp + 64) : zero8;
  }

  f32x4 oacc[4][5];
#pragma unroll
  for (int mi = 0; mi < 4; mi++)
#pragma unroll
    for (int dt = 0; dt < 5; dt++)
      oacc[mi][dt] = (f32x4){0.f, 0.f, 0.f, 0.f};
  float mrun[4][4], lrun[4][4];
#pragma unroll
  for (int mi = 0; mi < 4; mi++)
#pragma unroll
    for (int i = 0; i < 4; i++) { mrun[mi][i] = -1e30f; lrun[mi][i] = 0.f; }

  uint16_t* psw = &Ps[wave * 64 * PS_STRIDE];

  for (int c = 0; c < 4; c++) {
    __syncthreads();
    for (int idx = tid; idx < 576; idx += 256) {
      const int rr = idx / 9, cc = idx - rr * 9;
      const uint16_t* kg = qkv + (rowbase + c * 64 + rr) * 3456 + 1152 + h * 72 + cc * 8;
      *(uint4*)&Ks[rr * AK_STRIDE + cc * 8] = *(const uint4*)kg;
      uint4 vv = *(const uint4*)(kg + 1152);
      const uint16_t* e = (const uint16_t*)&vv;
#pragma unroll
      for (int j = 0; j < 8; j++) Vt[(cc * 8 + j) * VT_STRIDE + rr] = e[j];
    }
    __syncthreads();

    f32x4 s[4][4];
#pragma unroll
    for (int mi = 0; mi < 4; mi++)
#pragma unroll
      for (int ni = 0; ni < 4; ni++)
        s[mi][ni] = (f32x4){0.f, 0.f, 0.f, 0.f};
#pragma unroll
    for (int ni = 0; ni < 4; ni++) {
      bf16x8 kf0 = *(const bf16x8*)&Ks[(ni * 16 + l15) * AK_STRIDE + quad * 8];
      bf16x8 kf1 = *(const bf16x8*)&Ks[(ni * 16 + l15) * AK_STRIDE + 32 + quad * 8];
      bf16x8 kf2 = (quad == 0) ? *(const bf16x8*)&Ks[(ni * 16 + l15) * AK_STRIDE + 64] : zero8;
#pragma unroll
      for (int mi = 0; mi < 4; mi++) {
        s[mi][ni] = __builtin_amdgcn_mfma_f32_16x16x32_bf16(qf[mi][0], kf0, s[mi][ni], 0, 0, 0);
        s[mi][ni] = __builtin_amdgcn_mfma_f32_16x16x32_bf16(qf[mi][1], kf1, s[mi][ni], 0, 0, 0);
        s[mi][ni] = __builtin_amdgcn_mfma_f32_16x16x32_bf16(qf[mi][2], kf2, s[mi][ni], 0, 0, 0);
      }
    }

#pragma unroll
    for (int mi = 0; mi < 4; mi++) {
#pragma unroll
      for (int i = 0; i < 4; i++) {
        float mx = fmaxf(fmaxf(s[mi][0][i], s[mi][1][i]), fmaxf(s[mi][2][i], s[mi][3][i])) * scale;
#pragma unroll
        for (int d = 1; d < 16; d <<= 1) mx = fmaxf(mx, __shfl_xor(mx, d));
        const float mnew = fmaxf(mrun[mi][i], mx);
        const float corr = __expf(mrun[mi][i] - mnew);
        mrun[mi][i] = mnew;
        float psum = 0.f;
#pragma unroll
        for (int ni = 0; ni < 4; ni++) {
          const float p = __expf(s[mi][ni][i] * scale - mnew);
          s[mi][ni][i] = p;
          psum += p;
        }
#pragma unroll
        for (int d = 1; d < 16; d <<= 1) psum += __shfl_xor(psum, d);
        lrun[mi][i] = lrun[mi][i] * corr + psum;
#pragma unroll
        for (int dt = 0; dt < 5; dt++) oacc[mi][dt][i] *= corr;
      }
    }

#pragma unroll
    for (int mi = 0; mi < 4; mi++)
#pragma unroll
      for (int ni = 0; ni < 4; ni++)
#pragma unroll
        for (int i = 0; i < 4; i++)
          psw[(mi * 16 + quad * 4 + i) * PS_STRIDE + ni * 16 + l15] = f2b(s[mi][ni][i]);

#pragma unroll
    for (int kk = 0; kk < 2; kk++) {
      bf16x8 pf[4];
#pragma unroll
      for (int mi = 0; mi < 4; mi++)
        pf[mi] = *(const bf16x8*)&psw[(mi * 16 + l15) * PS_STRIDE + kk * 32 + quad * 8];
#pragma unroll
      for (int dt = 0; dt < 5; dt++) {
        bf16x8 vf = *(const bf16x8*)&Vt[(dt * 16 + l15) * VT_STRIDE + kk * 32 + quad * 8];
#pragma unroll
        for (int mi = 0; mi < 4; mi++)
          oacc[mi][dt] = __builtin_amdgcn_mfma_f32_16x16x32_bf16(pf[mi], vf, oacc[mi][dt], 0, 0, 0);
      }
    }
  }

#pragma unroll
  for (int mi = 0; mi < 4; mi++) {
#pragma unroll
    for (int i = 0; i < 4; i++) {
      const float inv = 1.f / lrun[mi][i];
      const size_t orow = rowbase + wave * 64 + mi * 16 + quad * 4 + i;
#pragma unroll
      for (int dt = 0; dt < 5; dt++) {
        const int d = dt * 16 + l15;
        if (d < 72) out[orow * 1152 + h * 72 + d] = f2b(oacc[mi][dt][i] * inv);
      }
    }
  }
}

// ---------------- temporal attention (T=16): scalar, small FLOPs ----------------
__global__ __launch_bounds__(128) void attn_t_k(
    const uint16_t* __restrict__ qkv, uint16_t* __restrict__ out)
{
  const int blk = blockIdx.x;
  const int bl = blk >> 1, hg = blk & 1;
  const int b = bl >> 8, l = bl & 255;
  const int tid = threadIdx.x;
  const int hh = tid >> 4, tq = tid & 15;
  const int h = hg * 8 + hh;
  __shared__ __align__(16) uint16_t kb[8 * 16 * 72];
  __shared__ __align__(16) uint16_t vb[8 * 16 * 72];

#pragma unroll
  for (int it = 0; it < 9; it++) {
    const int idx = tid + it * 128;
    const int rowL = idx / 9, cc = idx % 9;
    const int hhL = rowL >> 4, tL = rowL & 15;
    const size_t grow = (size_t)b * 4096 + (size_t)tL * 256 + l;
    const int colk = 1152 + (hg * 8 + hhL) * 72 + cc * 8;
    ((uint4*)&kb[rowL * 72])[cc] = *(const uint4*)(qkv + grow * 3456 + colk);
    ((uint4*)&vb[rowL * 72])[cc] = *(const uint4*)(qkv + grow * 3456 + colk + 1152);
  }
  __syncthreads();

  float q[72];
  const size_t qrow = (size_t)b * 4096 + (size_t)tq * 256 + l;
  {
    const uint16_t* qp = qkv + qrow * 3456 + h * 72;
#pragma unroll
    for (int i = 0; i < 9; i++) unpack8(((const uint4*)qp)[i], q + i * 8);
  }
  const float scale = 0.1178511301977579f;
  float s[16];
#pragma unroll
  for (int m = 0; m < 16; m++) {
    const uint4* kr = (const uint4*)&kb[(hh * 16 + m) * 72];
    float a = 0.f;
#pragma unroll
    for (int i = 0; i < 9; i++) {
      float kf[8]; unpack8(kr[i], kf);
#pragma unroll
      for (int j = 0; j < 8; j++) a += q[i * 8 + j] * kf[j];
    }
    s[m] = a * scale;
  }
  float mx = -1e30f;
#pragma unroll
  for (int m = 0; m < 16; m++) mx = fmaxf(mx, s[m]);
  float sum = 0.f;
#pragma unroll
  for (int m = 0; m < 16; m++) { s[m] = __expf(s[m] - mx); sum += s[m]; }
  const float inv = 1.f / sum;
  float o[72];
#pragma unroll
  for (int d = 0; d < 72; d++) o[d] = 0.f;
#pragma unroll
  for (int m = 0; m < 16; m++) {
    const float p = s[m];
    const uint4* vr = (const uint4*)&vb[(hh * 16 + m) * 72];
#pragma unroll
    for (int i = 0; i < 9; i++) {
      float vf[8]; unpack8(vr[i], vf);
#pragma unroll
      for (int j = 0; j < 8; j++) o[i * 8 + j] += p * vf[j];
    }
  }
  uint16_t* op = out + qrow * 1152 + h * 72;
#pragma unroll
  for (int d = 0; d < 72; d++) op[d] = f2b(o[d] * inv);
}

// ---------------- transpose + fp32->bf16: in(KxN) -> out(NxK) ----------------
__global__ __launch_bounds__(256) void transcvt_k(
    const float* __restrict__ in, uint16_t* __restrict__ out, int K, int N)
{
  __shared__ float t[32][33];
  const int n0 = blockIdx.x * 32, k0 = blockIdx.y * 32;
  const int tx = threadIdx.x & 31, ty = threadIdx.x >> 5;
#pragma unroll
  for (int i = 0; i < 32; i += 8)
    t[ty + i][tx] = in[(size_t)(k0 + ty + i) * N + n0 + tx];
  __syncthreads();
#pragma unroll
  for (int i = 0; i < 32; i += 8)
    out[(size_t)(n0 + ty + i) * K + k0 + tx] = f2b(t[tx][ty + i]);
}

// ---------------- swiglu ----------------
__global__ __launch_bounds__(256) void swiglu_k(
    const uint16_t* __restrict__ x1, const uint16_t* __restrict__ x2, uint16_t* __restrict__ h)
{
  const size_t i = ((size_t)blockIdx.x * 256 + threadIdx.x) * 8;
  float a[8], bb[8];
  unpack8(*(const uint4*)(x1 + i), a);
  unpack8(*(const uint4*)(x2 + i), bb);
  uint32_t r[4];
#pragma unroll
  for (int j = 0; j < 4; j++) {
    const float s0 = a[2 * j]     / (1.f + __expf(-a[2 * j]))     * bb[2 * j];
    const float s1 = a[2 * j + 1] / (1.f + __expf(-a[2 * j + 1])) * bb[2 * j + 1];
    r[j] = (uint32_t)f2b(s0) | ((uint32_t)f2b(s1) << 16);
  }
  *(uint4*)(h + i) = make_uint4(r[0], r[1], r[2], r[3]);
}

// ---------------- ada path ----------------
__global__ void siluc_k(const float* __restrict__ c, float* __restrict__ cs) {
  const int i = blockIdx.x * 256 + threadIdx.x;
  if (i < 2304) { const float v = c[i]; cs[i] = v / (1.f + __expf(-v)); }
}
__global__ __launch_bounds__(256) void ada_k(
    const float* __restrict__ cs, const float* __restrict__ W,
    const float* __restrict__ bias, float* __restrict__ chv)
{
  const int col = blockIdx.x * 256 + threadIdx.x;
  if (col >= 10368) return;
  float s0 = bias[col], s1 = bias[col];
  for (int k = 0; k < 1152; k++) {
    const float wv = W[(size_t)k * 10368 + col];
    s0 += cs[k] * wv;
    s1 += cs[1152 + k] * wv;
  }
  chv[col] = s0;
  chv[10368 + col] = s1;
}

extern "C" void kernel_launch(void* const* d_in, const int* in_sizes, int n_in,
                              void* d_out, int out_size, void* d_ws, size_t ws_size,
                              hipStream_t stream)
{
  const float* c_in    = (const float*)d_in[1];
  const float* norm1w  = (const float*)d_in[2];
  const float* norm2w  = (const float*)d_in[3];
  const float* norm3w  = (const float*)d_in[4];
  const float* qn_s    = (const float*)d_in[5];
  const float* kn_s    = (const float*)d_in[6];
  const float* qkv_s_w = (const float*)d_in[7];
  const float* qkv_s_b = (const float*)d_in[8];
  const float* proj_s_w= (const float*)d_in[9];
  const float* proj_s_b= (const float*)d_in[10];
  const float* qn_t    = (const float*)d_in[11];
  const float* kn_t    = (const float*)d_in[12];
  const float* qkv_t_w = (const float*)d_in[13];
  const float* qkv_t_b = (const float*)d_in[14];
  const float* proj_t_w= (const float*)d_in[15];
  const float* proj_t_b= (const float*)d_in[16];
  const float* w12_w   = (const float*)d_in[17];
  const float* w12_b   = (const float*)d_in[18];
  const float* w3_w    = (const float*)d_in[19];
  const float* w3_b    = (const float*)d_in[20];
  const float* ada_w   = (const float*)d_in[21];
  const float* ada_b   = (const float*)d_in[22];

  float* X = (float*)d_out;  // fp32 residual accumulator; also final output

  char* wsb = (char*)d_ws; size_t off = 0;
  auto alloc = [&](size_t bytes) -> void* {
    void* p = wsb + off; off += bytes; off = (off + 255) & ~(size_t)255; return p;
  };
  uint16_t* XN    = (uint16_t*)alloc((size_t)8192 * 1152 * 2);  // xn / attn_out
  uint16_t* QKV   = (uint16_t*)alloc((size_t)8192 * 3456 * 2);  // qkv / x1 / h
  uint16_t* X2    = (uint16_t*)alloc((size_t)8192 * 3072 * 2);
  uint16_t* WqkvS = (uint16_t*)alloc((size_t)3456 * 1152 * 2);
  uint16_t* WprojS= (uint16_t*)alloc((size_t)1152 * 1152 * 2);
  uint16_t* WqkvT = (uint16_t*)alloc((size_t)3456 * 1152 * 2);
  uint16_t* WprojT= (uint16_t*)alloc((size_t)1152 * 1152 * 2);
  uint16_t* W12T  = (uint16_t*)alloc((size_t)6144 * 1152 * 2);
  uint16_t* W3T   = (uint16_t*)alloc((size_t)1152 * 3072 * 2);
  float* CH = (float*)alloc((size_t)2 * 10368 * 4);
  float* CS = (float*)alloc((size_t)2 * 1152 * 4);

  hipMemcpyAsync(X, d_in[0], (size_t)8192 * 1152 * 4, hipMemcpyDeviceToDevice, stream);
  siluc_k<<<9, 256, 0, stream>>>(c_in, CS);
  ada_k<<<41, 256, 0, stream>>>(CS, ada_w, ada_b, CH);

  transcvt_k<<<dim3(3456 / 32, 1152 / 32), 256, 0, stream>>>(qkv_s_w, WqkvS, 1152, 3456);
  transcvt_k<<<dim3(1152 / 32, 1152 / 32), 256, 0, stream>>>(proj_s_w, WprojS, 1152, 1152);
  transcvt_k<<<dim3(3456 / 32, 1152 / 32), 256, 0, stream>>>(qkv_t_w, WqkvT, 1152, 3456);
  transcvt_k<<<dim3(1152 / 32, 1152 / 32), 256, 0, stream>>>(proj_t_w, WprojT, 1152, 1152);
  transcvt_k<<<dim3(6144 / 32, 1152 / 32), 256, 0, stream>>>(w12_w, W12T, 1152, 6144);
  transcvt_k<<<dim3(1152 / 32, 3072 / 32), 256, 0, stream>>>(w3_w, W3T, 3072, 1152);

  // ---- spatial attention ----
  rmsnorm_k<<<8192, 256, 0, stream>>>(X, norm1w, CH, 0, 1, XN);
  gemm_k<<<27 * 64, 256, 0, stream>>>(XN, WqkvS, qkv_s_b, QKV, nullptr, nullptr, nullptr,
                                      3456, 1152, 0);
  qknorm_k<<<1024, 256, 0, stream>>>(QKV, qn_s, kn_s);
  attn_s_k<<<512, 256, 0, stream>>>(QKV, XN);
  gemm_k<<<9 * 64, 256, 0, stream>>>(XN, WprojS, proj_s_b, nullptr, X, X, CH + 2 * 1152,
                                     1152, 1152, 1);

  // ---- temporal attention ----
  rmsnorm_k<<<8192, 256, 0, stream>>>(X, norm2w, CH, 3, 4, XN);
  gemm_k<<<27 * 64, 256, 0, stream>>>(XN, WqkvT, qkv_t_b, QKV, nullptr, nullptr, nullptr,
                                      3456, 1152, 0);
  qknorm_k<<<1024, 256, 0, stream>>>(QKV, qn_t, kn_t);
  attn_t_k<<<1024, 128, 0, stream>>>(QKV, XN);
  gemm_k<<<9 * 64, 256, 0, stream>>>(XN, WprojT, proj_t_b, nullptr, X, X, CH + 5 * 1152,
                                     1152, 1152, 1);

  // ---- MLP ----
  rmsnorm_k<<<8192, 256, 0, stream>>>(X, norm3w, CH, 6, 7, XN);
  gemm_k<<<24 * 64, 256, 0, stream>>>(XN, W12T, w12_b, QKV, nullptr, nullptr, nullptr,
                                      3072, 1152, 0);
  gemm_k<<<24 * 64, 256, 0, stream>>>(XN, W12T + (size_t)3072 * 1152, w12_b + 3072, X2,
                                      nullptr, nullptr, nullptr, 3072, 1152, 0);
  swiglu_k<<<12288, 256, 0, stream>>>(QKV, X2, QKV);
  gemm_k<<<9 * 64, 256, 0, stream>>>(QKV, W3T, w3_b, nullptr, X, X, CH + 8 * 1152,
                                     1152, 3072, 1);
}

// Round 4
// 1109.403 us; speedup vs baseline: 1.3254x; 1.0671x over previous
//
#include <hip/hip_runtime.h>
#include <stdint.h>

typedef __bf16 bf16x8 __attribute__((ext_vector_type(8)));
typedef float f32x4 __attribute__((ext_vector_type(4)));

__device__ __forceinline__ float b2f(uint32_t u) {
  union { uint32_t i; float f; } v; v.i = u << 16; return v.f;
}
__device__ __forceinline__ uint16_t f2b(float f) {
  union { float f; uint32_t i; } v; v.f = f;
  uint32_t r = (v.i + 0x7fffu + ((v.i >> 16) & 1u)) >> 16;
  return (uint16_t)r;
}
__device__ __forceinline__ void unpack8(uint4 u, float* f) {
  f[0] = b2f(u.x & 0xffffu); f[1] = b2f(u.x >> 16);
  f[2] = b2f(u.y & 0xffffu); f[3] = b2f(u.y >> 16);
  f[4] = b2f(u.z & 0xffffu); f[5] = b2f(u.z >> 16);
  f[6] = b2f(u.w & 0xffffu); f[7] = b2f(u.w >> 16);
}

__device__ __forceinline__ void gl2lds16(const void* g, void* l) {
  __builtin_amdgcn_global_load_lds(
      (const __attribute__((address_space(1))) void*)g,
      (__attribute__((address_space(3))) void*)l, 16, 0, 0);
}

// ---------------- Generic bf16 GEMM: C(MxN) = A(MxK) * Bt(NxK)^T ----------------
// M fixed at 8192 (64 m-tiles). XCD-aware swizzle: xcd = blockIdx&7 owns m-tiles
// [8*xcd, 8*xcd+8); within XCD, m fastest then n -> per-XCD L2 working set =
// A-panel (2.4 MB @ K=1152) + small B-tile window. Double-buffered async staging.
// mode 0: outb[r*N+c] = bf16(acc + bias[c])
// mode 1: outf[r*N+c] = resid[r*N+c] + gate[(r>>12)*10368 + c] * (acc + bias[c])
__global__ __launch_bounds__(256) void gemm_k(
    const uint16_t* __restrict__ A, const uint16_t* __restrict__ Bt,
    const float* __restrict__ bias,
    uint16_t* __restrict__ outb,
    float* __restrict__ outf, const float* __restrict__ resid,
    const float* __restrict__ gate,
    int N, int K, int mode)
{
  __shared__ __align__(16) uint16_t As[2][128 * 32];
  __shared__ __align__(16) uint16_t Bs[2][128 * 32];
  const int tid = threadIdx.x;
  // XCD-aware mapping (blocks round-robin XCDs by blockIdx%8)
  const int xcd = blockIdx.x & 7;
  const int slot = blockIdx.x >> 3;
  const int mt = xcd * 8 + (slot & 7);
  const int nt = slot >> 3;
  const int row0 = mt * 128, col0 = nt * 128;

  const int lane = tid & 63, wave = tid >> 6;
  const int l15 = lane & 15, quad = lane >> 4;
  const int wm = (wave & 1) * 64, wn = (wave >> 1) * 64;

  f32x4 acc[4][4];
  const f32x4 zero = {0.f, 0.f, 0.f, 0.f};
  for (int i = 0; i < 4; i++)
    for (int j = 0; j < 4; j++)
      acc[i][j] = zero;

  // staging: wave covers tile rows [wave*32, wave*32+32), two 16-row segments;
  // lane -> (row = seg*16 + lane>>2, 16B chunk = lane&3)
  const int rseg = wave * 32 + (lane >> 2);
  const int kseg8 = (lane & 3) * 8;
  const uint16_t* gA = A + (size_t)(row0 + rseg) * K + kseg8;
  const uint16_t* gB = Bt + (size_t)(col0 + rseg) * K + kseg8;
  const size_t rowK16 = (size_t)16 * K;
  const int woff = wave * 2048;

  // prologue: stage k0=0 into buffer 0
  gl2lds16(gA,          (char*)As[0] + woff);
  gl2lds16(gA + rowK16, (char*)As[0] + woff + 1024);
  gl2lds16(gB,          (char*)Bs[0] + woff);
  gl2lds16(gB + rowK16, (char*)Bs[0] + woff + 1024);

  for (int k0 = 0; k0 < K; k0 += 32) {
    const int cur = (k0 >> 5) & 1;
    __syncthreads();  // drains prefetch issued one iteration ago (full overlap)
    if (k0 + 32 < K) {
      const int nxt = cur ^ 1;
      gl2lds16(gA + k0 + 32,          (char*)As[nxt] + woff);
      gl2lds16(gA + rowK16 + k0 + 32, (char*)As[nxt] + woff + 1024);
      gl2lds16(gB + k0 + 32,          (char*)Bs[nxt] + woff);
      gl2lds16(gB + rowK16 + k0 + 32, (char*)Bs[nxt] + woff + 1024);
    }

    bf16x8 af[4], bfr[4];
#pragma unroll
    for (int i = 0; i < 4; i++) {
      af[i]  = *(const bf16x8*)&As[cur][(wm + i * 16 + l15) * 32 + quad * 8];
      bfr[i] = *(const bf16x8*)&Bs[cur][(wn + i * 16 + l15) * 32 + quad * 8];
    }
#pragma unroll
    for (int mi = 0; mi < 4; mi++)
#pragma unroll
      for (int ni = 0; ni < 4; ni++)
        acc[mi][ni] = __builtin_amdgcn_mfma_f32_16x16x32_bf16(af[mi], bfr[ni], acc[mi][ni], 0, 0, 0);
  }

#pragma unroll
  for (int mi = 0; mi < 4; mi++) {
#pragma unroll
    for (int ni = 0; ni < 4; ni++) {
      const int colg = col0 + wn + ni * 16 + l15;
      const float bv = bias ? bias[colg] : 0.f;
#pragma unroll
      for (int i = 0; i < 4; i++) {
        const int rowg = row0 + wm + mi * 16 + quad * 4 + i;
        const float v = acc[mi][ni][i] + bv;
        const size_t idx = (size_t)rowg * N + colg;
        if (mode == 0) {
          outb[idx] = f2b(v);
        } else {
          const int b = rowg >> 12;  // T*L = 4096 rows per batch
          outf[idx] = resid[idx] + gate[b * 10368 + colg] * v;
        }
      }
    }
  }
}

// ---------------- RMS + adaLN modulate ----------------
__global__ __launch_bounds__(256) void rmsnorm_k(
    const float* __restrict__ x, const float* __restrict__ w,
    const float* __restrict__ chv, int shsel, int scsel,
    uint16_t* __restrict__ xn)
{
  const int row = blockIdx.x;
  const int b = row >> 12;
  const float* xr = x + (size_t)row * 1152;
  float ss = 0.f;
  for (int d = threadIdx.x; d < 1152; d += 256) { const float v = xr[d]; ss += v * v; }
  for (int off = 32; off > 0; off >>= 1) ss += __shfl_down(ss, off);
  __shared__ float red[4];
  if ((threadIdx.x & 63) == 0) red[threadIdx.x >> 6] = ss;
  __syncthreads();
  const float tot = red[0] + red[1] + red[2] + red[3];
  const float rs = rsqrtf(tot * (1.f / 1152.f) + 1e-6f);
  const float* sh = chv + b * 10368 + shsel * 1152;
  const float* sc = chv + b * 10368 + scsel * 1152;
  uint16_t* xo = xn + (size_t)row * 1152;
  for (int d = threadIdx.x; d < 1152; d += 256)
    xo[d] = f2b(xr[d] * rs * w[d] * (1.f + sc[d]) + sh[d]);
}

// ---------------- per-head RMS norm of q,k in qkv (in place) ----------------
__global__ __launch_bounds__(256) void qknorm_k(
    uint16_t* __restrict__ qkv, const float* __restrict__ qn, const float* __restrict__ kn)
{
  const int tid = threadIdx.x;
  const int rl = tid >> 5, unit = tid & 31;
  const int h = unit & 15, isK = unit >> 4;
  const size_t row = (size_t)blockIdx.x * 8 + rl;
  uint16_t* p = qkv + row * 3456 + isK * 1152 + h * 72;
  const float* w = isK ? kn : qn;
  float v[72];
#pragma unroll
  for (int i = 0; i < 9; i++) unpack8(((const uint4*)p)[i], v + i * 8);
  float ss = 0.f;
#pragma unroll
  for (int d = 0; d < 72; d++) ss += v[d] * v[d];
  const float rs = rsqrtf(ss * (1.f / 72.f) + 1e-6f);
#pragma unroll
  for (int d = 0; d < 72; d++) p[d] = f2b(v[d] * rs * w[d]);
}

// ---------------- spatial attention, MFMA flash: block=(bt,h), 4 waves x 64 queries ----------------
#define AK_STRIDE 104
#define VT_STRIDE 88
#define PS_STRIDE 72
__global__ __launch_bounds__(256) void attn_s_k(
    const uint16_t* __restrict__ qkv, uint16_t* __restrict__ out)
{
  __shared__ __align__(16) uint16_t Ks[64 * AK_STRIDE];
  __shared__ __align__(16) uint16_t Vt[80 * VT_STRIDE];
  __shared__ __align__(16) uint16_t Ps[4 * 64 * PS_STRIDE];
  const int bh = blockIdx.x;
  const int bt = bh >> 4, h = bh & 15;
  const int tid = threadIdx.x;
  const int lane = tid & 63, wave = tid >> 6;
  const int l15 = lane & 15, quad = lane >> 4;
  const size_t rowbase = (size_t)bt * 256;
  const float scale = 0.1178511301977579f;  // 1/sqrt(72)

  union { uint4 u; bf16x8 v; } zu; zu.u = make_uint4(0, 0, 0, 0);
  const bf16x8 zero8 = zu.v;

  bf16x8 qf[4][3];
#pragma unroll
  for (int mi = 0; mi < 4; mi++) {
    const uint16_t* qp = qkv + (rowbase + wave * 64 + mi * 16 + l15) * 3456 + h * 72;
    qf[mi][0] = *(const bf16x8*)(qp + quad * 8);
    qf[mi][1] = *(const bf16x8*)(qp + 32 + quad * 8);
    qf[mi][2] = (quad == 0) ? *(const bf16x8*)(qp + 64) : zero8;
  }

  f32x4 oacc[4][5];
#pragma unroll
  for (int mi = 0; mi < 4; mi++)
#pragma unroll
    for (int dt = 0; dt < 5; dt++)
      oacc[mi][dt] = (f32x4){0.f, 0.f, 0.f, 0.f};
  float mrun[4][4], lrun[4][4];
#pragma unroll
  for (int mi = 0; mi < 4; mi++)
#pragma unroll
    for (int i = 0; i < 4; i++) { mrun[mi][i] = -1e30f; lrun[mi][i] = 0.f; }

  uint16_t* psw = &Ps[wave * 64 * PS_STRIDE];

  for (int c = 0; c < 4; c++) {
    __syncthreads();
    for (int idx = tid; idx < 576; idx += 256) {
      const int rr = idx / 9, cc = idx - rr * 9;
      const uint16_t* kg = qkv + (rowbase + c * 64 + rr) * 3456 + 1152 + h * 72 + cc * 8;
      *(uint4*)&Ks[rr * AK_STRIDE + cc * 8] = *(const uint4*)kg;
      uint4 vv = *(const uint4*)(kg + 1152);
      const uint16_t* e = (const uint16_t*)&vv;
#pragma unroll
      for (int j = 0; j < 8; j++) Vt[(cc * 8 + j) * VT_STRIDE + rr] = e[j];
    }
    __syncthreads();

    f32x4 s[4][4];
#pragma unroll
    for (int mi = 0; mi < 4; mi++)
#pragma unroll
      for (int ni = 0; ni < 4; ni++)
        s[mi][ni] = (f32x4){0.f, 0.f, 0.f, 0.f};
#pragma unroll
    for (int ni = 0; ni < 4; ni++) {
      bf16x8 kf0 = *(const bf16x8*)&Ks[(ni * 16 + l15) * AK_STRIDE + quad * 8];
      bf16x8 kf1 = *(const bf16x8*)&Ks[(ni * 16 + l15) * AK_STRIDE + 32 + quad * 8];
      bf16x8 kf2 = (quad == 0) ? *(const bf16x8*)&Ks[(ni * 16 + l15) * AK_STRIDE + 64] : zero8;
#pragma unroll
      for (int mi = 0; mi < 4; mi++) {
        s[mi][ni] = __builtin_amdgcn_mfma_f32_16x16x32_bf16(qf[mi][0], kf0, s[mi][ni], 0, 0, 0);
        s[mi][ni] = __builtin_amdgcn_mfma_f32_16x16x32_bf16(qf[mi][1], kf1, s[mi][ni], 0, 0, 0);
        s[mi][ni] = __builtin_amdgcn_mfma_f32_16x16x32_bf16(qf[mi][2], kf2, s[mi][ni], 0, 0, 0);
      }
    }

#pragma unroll
    for (int mi = 0; mi < 4; mi++) {
#pragma unroll
      for (int i = 0; i < 4; i++) {
        float mx = fmaxf(fmaxf(s[mi][0][i], s[mi][1][i]), fmaxf(s[mi][2][i], s[mi][3][i])) * scale;
#pragma unroll
        for (int d = 1; d < 16; d <<= 1) mx = fmaxf(mx, __shfl_xor(mx, d));
        const float mnew = fmaxf(mrun[mi][i], mx);
        const float corr = __expf(mrun[mi][i] - mnew);
        mrun[mi][i] = mnew;
        float psum = 0.f;
#pragma unroll
        for (int ni = 0; ni < 4; ni++) {
          const float p = __expf(s[mi][ni][i] * scale - mnew);
          s[mi][ni][i] = p;
          psum += p;
        }
#pragma unroll
        for (int d = 1; d < 16; d <<= 1) psum += __shfl_xor(psum, d);
        lrun[mi][i] = lrun[mi][i] * corr + psum;
#pragma unroll
        for (int dt = 0; dt < 5; dt++) oacc[mi][dt][i] *= corr;
      }
    }

#pragma unroll
    for (int mi = 0; mi < 4; mi++)
#pragma unroll
      for (int ni = 0; ni < 4; ni++)
#pragma unroll
        for (int i = 0; i < 4; i++)
          psw[(mi * 16 + quad * 4 + i) * PS_STRIDE + ni * 16 + l15] = f2b(s[mi][ni][i]);

#pragma unroll
    for (int kk = 0; kk < 2; kk++) {
      bf16x8 pf[4];
#pragma unroll
      for (int mi = 0; mi < 4; mi++)
        pf[mi] = *(const bf16x8*)&psw[(mi * 16 + l15) * PS_STRIDE + kk * 32 + quad * 8];
#pragma unroll
      for (int dt = 0; dt < 5; dt++) {
        bf16x8 vf = *(const bf16x8*)&Vt[(dt * 16 + l15) * VT_STRIDE + kk * 32 + quad * 8];
#pragma unroll
        for (int mi = 0; mi < 4; mi++)
          oacc[mi][dt] = __builtin_amdgcn_mfma_f32_16x16x32_bf16(pf[mi], vf, oacc[mi][dt], 0, 0, 0);
      }
    }
  }

#pragma unroll
  for (int mi = 0; mi < 4; mi++) {
#pragma unroll
    for (int i = 0; i < 4; i++) {
      const float inv = 1.f / lrun[mi][i];
      const size_t orow = rowbase + wave * 64 + mi * 16 + quad * 4 + i;
#pragma unroll
      for (int dt = 0; dt < 5; dt++) {
        const int d = dt * 16 + l15;
        if (d < 72) out[orow * 1152 + h * 72 + d] = f2b(oacc[mi][dt][i] * inv);
      }
    }
  }
}

// ---------------- temporal attention (T=16): scalar, small FLOPs ----------------
__global__ __launch_bounds__(128) void attn_t_k(
    const uint16_t* __restrict__ qkv, uint16_t* __restrict__ out)
{
  const int blk = blockIdx.x;
  const int bl = blk >> 1, hg = blk & 1;
  const int b = bl >> 8, l = bl & 255;
  const int tid = threadIdx.x;
  const int hh = tid >> 4, tq = tid & 15;
  const int h = hg * 8 + hh;
  __shared__ __align__(16) uint16_t kb[8 * 16 * 72];
  __shared__ __align__(16) uint16_t vb[8 * 16 * 72];

#pragma unroll
  for (int it = 0; it < 9; it++) {
    const int idx = tid + it * 128;
    const int rowL = idx / 9, cc = idx % 9;
    const int hhL = rowL >> 4, tL = rowL & 15;
    const size_t grow = (size_t)b * 4096 + (size_t)tL * 256 + l;
    const int colk = 1152 + (hg * 8 + hhL) * 72 + cc * 8;
    ((uint4*)&kb[rowL * 72])[cc] = *(const uint4*)(qkv + grow * 3456 + colk);
    ((uint4*)&vb[rowL * 72])[cc] = *(const uint4*)(qkv + grow * 3456 + colk + 1152);
  }
  __syncthreads();

  float q[72];
  const size_t qrow = (size_t)b * 4096 + (size_t)tq * 256 + l;
  {
    const uint16_t* qp = qkv + qrow * 3456 + h * 72;
#pragma unroll
    for (int i = 0; i < 9; i++) unpack8(((const uint4*)qp)[i], q + i * 8);
  }
  const float scale = 0.1178511301977579f;
  float s[16];
#pragma unroll
  for (int m = 0; m < 16; m++) {
    const uint4* kr = (const uint4*)&kb[(hh * 16 + m) * 72];
    float a = 0.f;
#pragma unroll
    for (int i = 0; i < 9; i++) {
      float kf[8]; unpack8(kr[i], kf);
#pragma unroll
      for (int j = 0; j < 8; j++) a += q[i * 8 + j] * kf[j];
    }
    s[m] = a * scale;
  }
  float mx = -1e30f;
#pragma unroll
  for (int m = 0; m < 16; m++) mx = fmaxf(mx, s[m]);
  float sum = 0.f;
#pragma unroll
  for (int m = 0; m < 16; m++) { s[m] = __expf(s[m] - mx); sum += s[m]; }
  const float inv = 1.f / sum;
  float o[72];
#pragma unroll
  for (int d = 0; d < 72; d++) o[d] = 0.f;
#pragma unroll
  for (int m = 0; m < 16; m++) {
    const float p = s[m];
    const uint4* vr = (const uint4*)&vb[(hh * 16 + m) * 72];
#pragma unroll
    for (int i = 0; i < 9; i++) {
      float vf[8]; unpack8(vr[i], vf);
#pragma unroll
      for (int j = 0; j < 8; j++) o[i * 8 + j] += p * vf[j];
    }
  }
  uint16_t* op = out + qrow * 1152 + h * 72;
#pragma unroll
  for (int d = 0; d < 72; d++) op[d] = f2b(o[d] * inv);
}

// ---------------- transpose + fp32->bf16: in(KxN) -> out(NxK) ----------------
__global__ __launch_bounds__(256) void transcvt_k(
    const float* __restrict__ in, uint16_t* __restrict__ out, int K, int N)
{
  __shared__ float t[32][33];
  const int n0 = blockIdx.x * 32, k0 = blockIdx.y * 32;
  const int tx = threadIdx.x & 31, ty = threadIdx.x >> 5;
#pragma unroll
  for (int i = 0; i < 32; i += 8)
    t[ty + i][tx] = in[(size_t)(k0 + ty + i) * N + n0 + tx];
  __syncthreads();
#pragma unroll
  for (int i = 0; i < 32; i += 8)
    out[(size_t)(n0 + ty + i) * K + k0 + tx] = f2b(t[tx][ty + i]);
}

// ---------------- swiglu ----------------
__global__ __launch_bounds__(256) void swiglu_k(
    const uint16_t* __restrict__ x1, const uint16_t* __restrict__ x2, uint16_t* __restrict__ h)
{
  const size_t i = ((size_t)blockIdx.x * 256 + threadIdx.x) * 8;
  float a[8], bb[8];
  unpack8(*(const uint4*)(x1 + i), a);
  unpack8(*(const uint4*)(x2 + i), bb);
  uint32_t r[4];
#pragma unroll
  for (int j = 0; j < 4; j++) {
    const float s0 = a[2 * j]     / (1.f + __expf(-a[2 * j]))     * bb[2 * j];
    const float s1 = a[2 * j + 1] / (1.f + __expf(-a[2 * j + 1])) * bb[2 * j + 1];
    r[j] = (uint32_t)f2b(s0) | ((uint32_t)f2b(s1) << 16);
  }
  *(uint4*)(h + i) = make_uint4(r[0], r[1], r[2], r[3]);
}

// ---------------- ada path ----------------
__global__ void siluc_k(const float* __restrict__ c, float* __restrict__ cs) {
  const int i = blockIdx.x * 256 + threadIdx.x;
  if (i < 2304) { const float v = c[i]; cs[i] = v / (1.f + __expf(-v)); }
}
__global__ __launch_bounds__(256) void ada_k(
    const float* __restrict__ cs, const float* __restrict__ W,
    const float* __restrict__ bias, float* __restrict__ chv)
{
  const int col = blockIdx.x * 256 + threadIdx.x;
  if (col >= 10368) return;
  float s0 = bias[col], s1 = bias[col];
  for (int k = 0; k < 1152; k++) {
    const float wv = W[(size_t)k * 10368 + col];
    s0 += cs[k] * wv;
    s1 += cs[1152 + k] * wv;
  }
  chv[col] = s0;
  chv[10368 + col] = s1;
}

extern "C" void kernel_launch(void* const* d_in, const int* in_sizes, int n_in,
                              void* d_out, int out_size, void* d_ws, size_t ws_size,
                              hipStream_t stream)
{
  const float* c_in    = (const float*)d_in[1];
  const float* norm1w  = (const float*)d_in[2];
  const float* norm2w  = (const float*)d_in[3];
  const float* norm3w  = (const float*)d_in[4];
  const float* qn_s    = (const float*)d_in[5];
  const float* kn_s    = (const float*)d_in[6];
  const float* qkv_s_w = (const float*)d_in[7];
  const float* qkv_s_b = (const float*)d_in[8];
  const float* proj_s_w= (const float*)d_in[9];
  const float* proj_s_b= (const float*)d_in[10];
  const float* qn_t    = (const float*)d_in[11];
  const float* kn_t    = (const float*)d_in[12];
  const float* qkv_t_w = (const float*)d_in[13];
  const float* qkv_t_b = (const float*)d_in[14];
  const float* proj_t_w= (const float*)d_in[15];
  const float* proj_t_b= (const float*)d_in[16];
  const float* w12_w   = (const float*)d_in[17];
  const float* w12_b   = (const float*)d_in[18];
  const float* w3_w    = (const float*)d_in[19];
  const float* w3_b    = (const float*)d_in[20];
  const float* ada_w   = (const float*)d_in[21];
  const float* ada_b   = (const float*)d_in[22];

  float* X = (float*)d_out;  // fp32 residual accumulator; also final output

  char* wsb = (char*)d_ws; size_t off = 0;
  auto alloc = [&](size_t bytes) -> void* {
    void* p = wsb + off; off += bytes; off = (off + 255) & ~(size_t)255; return p;
  };
  uint16_t* XN    = (uint16_t*)alloc((size_t)8192 * 1152 * 2);  // xn / attn_out
  uint16_t* QKV   = (uint16_t*)alloc((size_t)8192 * 3456 * 2);  // qkv / x1 / h
  uint16_t* X2    = (uint16_t*)alloc((size_t)8192 * 3072 * 2);
  uint16_t* WqkvS = (uint16_t*)alloc((size_t)3456 * 1152 * 2);
  uint16_t* WprojS= (uint16_t*)alloc((size_t)1152 * 1152 * 2);
  uint16_t* WqkvT = (uint16_t*)alloc((size_t)3456 * 1152 * 2);
  uint16_t* WprojT= (uint16_t*)alloc((size_t)1152 * 1152 * 2);
  uint16_t* W12T  = (uint16_t*)alloc((size_t)6144 * 1152 * 2);
  uint16_t* W3T   = (uint16_t*)alloc((size_t)1152 * 3072 * 2);
  float* CH = (float*)alloc((size_t)2 * 10368 * 4);
  float* CS = (float*)alloc((size_t)2 * 1152 * 4);

  hipMemcpyAsync(X, d_in[0], (size_t)8192 * 1152 * 4, hipMemcpyDeviceToDevice, stream);
  siluc_k<<<9, 256, 0, stream>>>(c_in, CS);
  ada_k<<<41, 256, 0, stream>>>(CS, ada_w, ada_b, CH);

  transcvt_k<<<dim3(3456 / 32, 1152 / 32), 256, 0, stream>>>(qkv_s_w, WqkvS, 1152, 3456);
  transcvt_k<<<dim3(1152 / 32, 1152 / 32), 256, 0, stream>>>(proj_s_w, WprojS, 1152, 1152);
  transcvt_k<<<dim3(3456 / 32, 1152 / 32), 256, 0, stream>>>(qkv_t_w, WqkvT, 1152, 3456);
  transcvt_k<<<dim3(1152 / 32, 1152 / 32), 256, 0, stream>>>(proj_t_w, WprojT, 1152, 1152);
  transcvt_k<<<dim3(6144 / 32, 1152 / 32), 256, 0, stream>>>(w12_w, W12T, 1152, 6144);
  transcvt_k<<<dim3(1152 / 32, 3072 / 32), 256, 0, stream>>>(w3_w, W3T, 3072, 1152);

  // ---- spatial attention ----
  rmsnorm_k<<<8192, 256, 0, stream>>>(X, norm1w, CH, 0, 1, XN);
  gemm_k<<<27 * 64, 256, 0, stream>>>(XN, WqkvS, qkv_s_b, QKV, nullptr, nullptr, nullptr,
                                      3456, 1152, 0);
  qknorm_k<<<1024, 256, 0, stream>>>(QKV, qn_s, kn_s);
  attn_s_k<<<512, 256, 0, stream>>>(QKV, XN);
  gemm_k<<<9 * 64, 256, 0, stream>>>(XN, WprojS, proj_s_b, nullptr, X, X, CH + 2 * 1152,
                                     1152, 1152, 1);

  // ---- temporal attention ----
  rmsnorm_k<<<8192, 256, 0, stream>>>(X, norm2w, CH, 3, 4, XN);
  gemm_k<<<27 * 64, 256, 0, stream>>>(XN, WqkvT, qkv_t_b, QKV, nullptr, nullptr, nullptr,
                                      3456, 1152, 0);
  qknorm_k<<<1024, 256, 0, stream>>>(QKV, qn_t, kn_t);
  attn_t_k<<<1024, 128, 0, stream>>>(QKV, XN);
  gemm_k<<<9 * 64, 256, 0, stream>>>(XN, WprojT, proj_t_b, nullptr, X, X, CH + 5 * 1152,
                                     1152, 1152, 1);

  // ---- MLP ----
  rmsnorm_k<<<8192, 256, 0, stream>>>(X, norm3w, CH, 6, 7, XN);
  gemm_k<<<24 * 64, 256, 0, stream>>>(XN, W12T, w12_b, QKV, nullptr, nullptr, nullptr,
                                      3072, 1152, 0);
  gemm_k<<<24 * 64, 256, 0, stream>>>(XN, W12T + (size_t)3072 * 1152, w12_b + 3072, X2,
                                      nullptr, nullptr, nullptr, 3072, 1152, 0);
  swiglu_k<<<12288, 256, 0, stream>>>(QKV, X2, QKV);
  gemm_k<<<9 * 64, 256, 0, stream>>>(QKV, W3T, w3_b, nullptr, X, X, CH + 8 * 1152,
                                     1152, 3072, 1);
}